// Round 3
// baseline (5248.222 us; speedup 1.0000x reference)
//
#include <hip/hip_runtime.h>
#include <hip/hip_bf16.h>

using bf16 = __hip_bfloat16;

#define EDGES 25000
#define NNODES 5000
#define EPB 4
#define NBLK (EDGES / EPB)

__device__ __forceinline__ float sigmf(float x) { return 1.0f / (1.0f + expf(-x)); }

template<bool BF>
__device__ __forceinline__ float LD1(const void* p, size_t i) {
    if (BF) return __bfloat162float(((const bf16*)p)[i]);
    else    return ((const float*)p)[i];
}

template<bool BF>
__device__ __forceinline__ float4 LD4(const void* p, size_t i) {
    if (BF) {
        ushort4 u = *reinterpret_cast<const ushort4*>((const bf16*)p + i);
        float4 r;
        r.x = __uint_as_float((unsigned)u.x << 16);
        r.y = __uint_as_float((unsigned)u.y << 16);
        r.z = __uint_as_float((unsigned)u.z << 16);
        r.w = __uint_as_float((unsigned)u.w << 16);
        return r;
    } else {
        return *reinterpret_cast<const float4*>((const float*)p + i);
    }
}

__device__ __forceinline__ void fma4(float4& a, float s, const float4& w) {
    a.x += s * w.x; a.y += s * w.y; a.z += s * w.z; a.w += s * w.w;
}

__device__ __forceinline__ void silu4(float4& a) {
    a.x *= sigmf(a.x); a.y *= sigmf(a.y); a.z *= sigmf(a.z); a.w *= sigmf(a.w);
}

// monotone float<->uint encoding for atomicMax on floats
__device__ __forceinline__ unsigned encF(float f) {
    unsigned b = __float_as_uint(f);
    return (b & 0x80000000u) ? ~b : (b | 0x80000000u);
}
__device__ __forceinline__ float decF(unsigned e) {
    unsigned b = (e & 0x80000000u) ? (e ^ 0x80000000u) : ~e;
    return __uint_as_float(b);
}
#define ENC_NEGINF 0x007FFFFFu

// 8-deep pipelined single-row MAC: acc[e] += act[e][i..i+7] * W[i..i+7][j0..j0+3]
#define STREAM8_1(Wptr, LDW, j0, ACTEXPR, NACC) \
    { \
        float4 w0 = LD4<BF>(Wptr, (size_t)(i + 0) * (LDW) + (j0)); \
        float4 w1 = LD4<BF>(Wptr, (size_t)(i + 1) * (LDW) + (j0)); \
        float4 w2 = LD4<BF>(Wptr, (size_t)(i + 2) * (LDW) + (j0)); \
        float4 w3 = LD4<BF>(Wptr, (size_t)(i + 3) * (LDW) + (j0)); \
        float4 w4 = LD4<BF>(Wptr, (size_t)(i + 4) * (LDW) + (j0)); \
        float4 w5 = LD4<BF>(Wptr, (size_t)(i + 5) * (LDW) + (j0)); \
        float4 w6 = LD4<BF>(Wptr, (size_t)(i + 6) * (LDW) + (j0)); \
        float4 w7 = LD4<BF>(Wptr, (size_t)(i + 7) * (LDW) + (j0)); \
        _Pragma("unroll") \
        for (int e = 0; e < NACC; e++) { \
            const float* qa = ACTEXPR; \
            float4 a0 = *(const float4*)qa; \
            float4 a1 = *(const float4*)(qa + 4); \
            fma4(acc[e], a0.x, w0); fma4(acc[e], a0.y, w1); \
            fma4(acc[e], a0.z, w2); fma4(acc[e], a0.w, w3); \
            fma4(acc[e], a1.x, w4); fma4(acc[e], a1.y, w5); \
            fma4(acc[e], a1.z, w6); fma4(acc[e], a1.w, w7); \
        } \
    }

// 8-deep pipelined two-row MAC into ra[e], rb[e]
#define STREAM8_2(Wptr, LDW, j0, ACTA, ACTB) \
    { \
        float4 w0 = LD4<BF>(Wptr, (size_t)(i + 0) * (LDW) + (j0)); \
        float4 w1 = LD4<BF>(Wptr, (size_t)(i + 1) * (LDW) + (j0)); \
        float4 w2 = LD4<BF>(Wptr, (size_t)(i + 2) * (LDW) + (j0)); \
        float4 w3 = LD4<BF>(Wptr, (size_t)(i + 3) * (LDW) + (j0)); \
        float4 w4 = LD4<BF>(Wptr, (size_t)(i + 4) * (LDW) + (j0)); \
        float4 w5 = LD4<BF>(Wptr, (size_t)(i + 5) * (LDW) + (j0)); \
        float4 w6 = LD4<BF>(Wptr, (size_t)(i + 6) * (LDW) + (j0)); \
        float4 w7 = LD4<BF>(Wptr, (size_t)(i + 7) * (LDW) + (j0)); \
        _Pragma("unroll") \
        for (int e = 0; e < EPB; e++) { \
            const float* pa = ACTA; \
            const float* pb = ACTB; \
            float4 a0 = *(const float4*)pa; \
            float4 a1 = *(const float4*)(pa + 4); \
            float4 b0 = *(const float4*)pb; \
            float4 b1 = *(const float4*)(pb + 4); \
            fma4(ra[e], a0.x, w0); fma4(ra[e], a0.y, w1); \
            fma4(ra[e], a0.z, w2); fma4(ra[e], a0.w, w3); \
            fma4(ra[e], a1.x, w4); fma4(ra[e], a1.y, w5); \
            fma4(ra[e], a1.z, w6); fma4(ra[e], a1.w, w7); \
            fma4(rb[e], b0.x, w0); fma4(rb[e], b0.y, w1); \
            fma4(rb[e], b0.z, w2); fma4(rb[e], b0.w, w3); \
            fma4(rb[e], b1.x, w4); fma4(rb[e], b1.y, w5); \
            fma4(rb[e], b1.z, w6); fma4(rb[e], b1.w, w7); \
        } \
    }

// ---------------- dtype detector ----------------
__global__ void k_detect(const void* edge_dist, int* flag) {
    if (threadIdx.x == 0 && blockIdx.x == 0) {
        const bf16* p = (const bf16*)edge_dist;
        int ok = 1;
        for (int i = 0; i < 256; i++) {
            float v = __bfloat162float(p[i]);
            if (!(v >= 0.0f && v <= 1.0f)) { ok = 0; break; }
        }
        *flag = ok;
    }
}

// ---------------- fill ----------------
__global__ void k_fill(float* accb, float* nden, unsigned* nmax) {
    int tid = blockIdx.x * 256 + threadIdx.x;
    if (tid < NNODES * 1600) accb[tid] = 0.0f;
    if (tid < NNODES * 8) { nden[tid] = 0.0f; nmax[tid] = ENC_NEGINF; }
}

// ---------------- alpha prepass: EPB=4, shared weights ----------------
// LDS floats: XE[768]@0 T1@768 H1@1024 T2@1280 H2@1536
// rad0[2560]@1792 x0[2560]@4352 R[4224]@6912 (X=R, WG=R+3200 | Y=R)
// extraA[1024]@11136 -> total 12160 floats = 48640 B -> 3 blocks/CU
template<bool BF>
__global__ __launch_bounds__(256, 3) void k_alpha(
    const void* __restrict__ node_feats, const void* __restrict__ edge_dist,
    const void* __restrict__ wigner, const void* __restrict__ emb_s,
    const void* __restrict__ emb_r,
    const void* __restrict__ rw1, const void* __restrict__ rb1,
    const void* __restrict__ rl1s, const void* __restrict__ rl1b,
    const void* __restrict__ rw2, const void* __restrict__ rb2,
    const void* __restrict__ rl2s, const void* __restrict__ rl2b,
    const void* __restrict__ rw3, const void* __restrict__ rb3,
    const void* __restrict__ c1w0, const void* __restrict__ c1b0,
    const void* __restrict__ an_s, const void* __restrict__ an_b,
    const void* __restrict__ adot,
    const int* __restrict__ species, const int* __restrict__ senders,
    const int* __restrict__ receivers, const int* __restrict__ dtf,
    float* __restrict__ alpha_out, unsigned* __restrict__ nmax)
{
    if ((*dtf != 0) != BF) return;
    __shared__ __align__(16) float sm[12160];
    float* XE   = sm;
    float* T1   = sm + 768;
    float* H1   = sm + 1024;
    float* T2   = sm + 1280;
    float* H2   = sm + 1536;
    float* rad0 = sm + 1792;
    float* x0   = sm + 4352;
    float* R    = sm + 6912;
    float* extraA = sm + 11136;

    const int t = threadIdx.x;
    const int e0 = blockIdx.x * EPB;
    const int eg = t >> 6, tt = t & 63;

    // ---- XE gather (edge-parallel) ----
    {
        int ee = e0 + eg;
        XE[eg * 192 + tt]       = LD1<BF>(edge_dist, (size_t)ee * 64 + tt);
        XE[eg * 192 + 64 + tt]  = LD1<BF>(emb_s, (size_t)species[senders[ee]] * 64 + tt);
        XE[eg * 192 + 128 + tt] = LD1<BF>(emb_r, (size_t)species[receivers[ee]] * 64 + tt);
    }
    __syncthreads();
    // ---- radial MLP (edge-parallel: 64 threads per edge) ----
    {
        float a = LD1<BF>(rb1, tt);
        #pragma unroll 4
        for (int k = 0; k < 192; k++) a += XE[eg * 192 + k] * LD1<BF>(rw1, k * 64 + tt);
        T1[eg * 64 + tt] = a;
    }
    __syncthreads();
    {
        float mu = 0.f;
        for (int k = 0; k < 64; k++) mu += T1[eg * 64 + k];
        mu *= (1.f / 64.f);
        float var = 0.f;
        for (int k = 0; k < 64; k++) { float d = T1[eg * 64 + k] - mu; var += d * d; }
        float xn = (T1[eg * 64 + tt] - mu) * rsqrtf(var * (1.f / 64.f) + 1e-6f) * LD1<BF>(rl1s, tt) + LD1<BF>(rl1b, tt);
        H1[eg * 64 + tt] = xn * sigmf(xn);
    }
    __syncthreads();
    {
        float a = LD1<BF>(rb2, tt);
        #pragma unroll 4
        for (int k = 0; k < 64; k++) a += H1[eg * 64 + k] * LD1<BF>(rw2, k * 64 + tt);
        T2[eg * 64 + tt] = a;
    }
    __syncthreads();
    {
        float mu = 0.f;
        for (int k = 0; k < 64; k++) mu += T2[eg * 64 + k];
        mu *= (1.f / 64.f);
        float var = 0.f;
        for (int k = 0; k < 64; k++) { float d = T2[eg * 64 + k] - mu; var += d * d; }
        float xn = (T2[eg * 64 + tt] - mu) * rsqrtf(var * (1.f / 64.f) + 1e-6f) * LD1<BF>(rl2s, tt) + LD1<BF>(rl2b, tt);
        H2[eg * 64 + tt] = xn * sigmf(xn);
    }
    __syncthreads();
    // ---- rad0: first 640 outputs of rad, weights shared across 4 edges ----
    if (t < 160) {
        int j0 = t * 4;
        float4 acc[EPB];
        float4 bv = LD4<BF>(rb3, j0);
        #pragma unroll
        for (int e = 0; e < EPB; e++) acc[e] = bv;
        for (int i = 0; i < 64; i += 8)
            STREAM8_1(rw3, 1536, j0, &H2[e * 64 + i], EPB)
        #pragma unroll
        for (int e = 0; e < EPB; e++) *(float4*)&rad0[e * 640 + j0] = acc[e];
    }
    __syncthreads();
    // ---- per-edge: X gather + rotate rows 0..4 + rad scale ----
    {
        float* X  = R;
        float* WG = R + 3200;
        for (int e = 0; e < EPB; e++) {
            int s_ = senders[e0 + e], r_ = receivers[e0 + e];
            for (int q = t; q < 800; q += 256) {
                int k = q >> 5, c0 = (q & 31) * 4;
                float4 v = (c0 < 64) ? LD4<BF>(node_feats, (size_t)s_ * 1600 + k * 64 + c0)
                                     : LD4<BF>(node_feats, (size_t)r_ * 1600 + k * 64 + (c0 - 64));
                *(float4*)&X[q * 4] = v;
            }
            for (int i = t; i < 125; i += 256) WG[i] = LD1<BF>(wigner, (size_t)(e0 + e) * 475 + i);
            __syncthreads();
            if (t < 160) {
                int m = t >> 5, c0 = (t & 31) * 4;
                float4 acc = make_float4(0.f, 0.f, 0.f, 0.f);
                #pragma unroll
                for (int k = 0; k < 25; k++) fma4(acc, WG[m * 25 + k], *(const float4*)&X[k * 128 + c0]);
                float4 rv = *(const float4*)&rad0[e * 640 + t * 4];
                acc.x *= rv.x; acc.y *= rv.y; acc.z *= rv.z; acc.w *= rv.w;
                *(float4*)&x0[e * 640 + t * 4] = acc;
            }
            __syncthreads();
        }
    }
    // ---- alpha matmul: cols [320,576), k split 4 ways, weights shared ----
    {
        float* Y = R;
        int col = t & 63, kq = t >> 6;
        int j0 = 320 + col * 4;
        int ibase = kq * 160;
        float4 acc[EPB];
        #pragma unroll
        for (int e = 0; e < EPB; e++) acc[e] = make_float4(0.f, 0.f, 0.f, 0.f);
        for (int i = ibase; i < ibase + 160; i += 8)
            STREAM8_1(c1w0, 640, j0, &x0[e * 640 + i], EPB)
        __syncthreads();  // R (X/WG) dead; Y overlays
        #pragma unroll
        for (int e = 0; e < EPB; e++) *(float4*)&Y[(e * 256 + kq * 64 + col) * 4] = acc[e];
        __syncthreads();
        {
            int e = t >> 6, c = t & 63;
            float4 s = LD4<BF>(c1b0, 320 + c * 4);
            #pragma unroll
            for (int q = 0; q < 4; q++) {
                float4 v = *(const float4*)&Y[(e * 256 + q * 64 + c) * 4];
                s.x += v.x; s.y += v.y; s.z += v.z; s.w += v.w;
            }
            *(float4*)&extraA[e * 256 + c * 4] = s;
        }
    }
    __syncthreads();
    if (t < 32) {
        int e = t >> 3, h = t & 7;
        float mu = 0.0f;
        for (int k = 0; k < 32; k++) mu += extraA[e * 256 + h * 32 + k];
        mu *= (1.0f / 32.0f);
        float var = 0.0f;
        for (int k = 0; k < 32; k++) { float d = extraA[e * 256 + h * 32 + k] - mu; var += d * d; }
        float rs = rsqrtf(var * (1.0f / 32.0f) + 1e-6f);
        float logit = 0.0f;
        for (int k = 0; k < 32; k++) {
            float xn = (extraA[e * 256 + h * 32 + k] - mu) * rs * LD1<BF>(an_s, k) + LD1<BF>(an_b, k);
            float slr = 0.6f * xn + 0.4f * xn * (2.0f * sigmf(xn) - 1.0f);
            logit += slr * LD1<BF>(adot, h * 32 + k);
        }
        int r = receivers[e0 + e];
        alpha_out[(size_t)(e0 + e) * 8 + h] = logit;
        atomicMax(&nmax[r * 8 + h], encF(logit));
    }
}

// ---------------- exp + denom ----------------
__global__ void k_exp(const int* __restrict__ receivers, const unsigned* __restrict__ nmax,
                      float* __restrict__ alpha, float* __restrict__ nden) {
    int tid = blockIdx.x * 256 + threadIdx.x;
    if (tid >= EDGES * 8) return;
    int e = tid >> 3, h = tid & 7;
    int r = receivers[e];
    float m = decF(nmax[r * 8 + h]);
    float ex = expf(alpha[tid] - m);
    alpha[tid] = ex;
    atomicAdd(&nden[r * 8 + h], ex);
}

// ---------------- mega2: 4 edges per block ----------------
// LDS map (floats, total 19744 = 77.1 KB -> 2 blocks/CU):
//   Q   [0,9728)      : EF1[e][2432] (P2-P3) | G(6400)+S2(2432) (P4) | EF3[e][2432] (P5-P7)
//   C   [9728,14592)  : P1 scratch | P2 X+wg | EF2[e][1216] (P3-P4) | P5 staging | P7 WV+EO
//   RAD [13408,19552) : radial out [e][1536] (live P1-P2 only)
//   YF  [14592,19456) : P3 m1 row-split staging (4096) + m2 staging | FEATS (P4-P5) | P7 EO tail
//   GAT [19456,19712) : gating [e][64] (P3-P4)
//   ALs [19712,19744) : alpha scale [e][8] (P7)
template<bool BF>
__global__ __launch_bounds__(256, 2) void k_mega2(
    const void* __restrict__ node_feats, const void* __restrict__ edge_dist,
    const void* __restrict__ wigner, const void* __restrict__ wigner_inv,
    const void* __restrict__ to_grid, const void* __restrict__ from_grid,
    const void* __restrict__ emb_s, const void* __restrict__ emb_r,
    const void* __restrict__ rw1, const void* __restrict__ rb1,
    const void* __restrict__ rl1s, const void* __restrict__ rl1b,
    const void* __restrict__ rw2, const void* __restrict__ rb2,
    const void* __restrict__ rl2s, const void* __restrict__ rl2b,
    const void* __restrict__ rw3, const void* __restrict__ rb3,
    const void* __restrict__ c1w0, const void* __restrict__ c1b0,
    const void* __restrict__ c1w1, const void* __restrict__ c1w2,
    const void* __restrict__ c2w0, const void* __restrict__ c2b0,
    const void* __restrict__ c2w1, const void* __restrict__ c2w2,
    const void* __restrict__ proj_w,
    const int* __restrict__ species, const int* __restrict__ senders,
    const int* __restrict__ receivers, const int* __restrict__ dtf,
    const float* __restrict__ alpha, const float* __restrict__ nden,
    float* __restrict__ accb)
{
    if ((*dtf != 0) != BF) return;
    __shared__ __align__(16) float sm[19744];
    float* Q   = sm;
    float* C   = sm + 9728;
    float* RAD = sm + 13408;
    float* YF  = sm + 14592;
    float* GAT = sm + 19456;
    float* ALs = sm + 19712;

    const int t = threadIdx.x;
    const int e0 = blockIdx.x * EPB;
    int snd[EPB], rcv[EPB];
    #pragma unroll
    for (int e = 0; e < EPB; e++) { snd[e] = senders[e0 + e]; rcv[e] = receivers[e0 + e]; }

    // ---- P1: radial MLP (edge-parallel 4x64; rw3 weights shared) ----
    {
        float* XE = C;
        float* T1 = C + 768;
        float* H1 = C + 1024;
        float* T2 = C + 1280;
        float* H2 = C + 1536;
        const int eg = t >> 6, tt = t & 63;
        {
            int ee = e0 + eg;
            XE[eg * 192 + tt]       = LD1<BF>(edge_dist, (size_t)ee * 64 + tt);
            XE[eg * 192 + 64 + tt]  = LD1<BF>(emb_s, (size_t)species[senders[ee]] * 64 + tt);
            XE[eg * 192 + 128 + tt] = LD1<BF>(emb_r, (size_t)species[receivers[ee]] * 64 + tt);
        }
        __syncthreads();
        {
            float a = LD1<BF>(rb1, tt);
            #pragma unroll 4
            for (int k = 0; k < 192; k++) a += XE[eg * 192 + k] * LD1<BF>(rw1, k * 64 + tt);
            T1[eg * 64 + tt] = a;
        }
        __syncthreads();
        {
            float mu = 0.f;
            for (int k = 0; k < 64; k++) mu += T1[eg * 64 + k];
            mu *= (1.f / 64.f);
            float var = 0.f;
            for (int k = 0; k < 64; k++) { float d = T1[eg * 64 + k] - mu; var += d * d; }
            float xn = (T1[eg * 64 + tt] - mu) * rsqrtf(var * (1.f / 64.f) + 1e-6f) * LD1<BF>(rl1s, tt) + LD1<BF>(rl1b, tt);
            H1[eg * 64 + tt] = xn * sigmf(xn);
        }
        __syncthreads();
        {
            float a = LD1<BF>(rb2, tt);
            #pragma unroll 4
            for (int k = 0; k < 64; k++) a += H1[eg * 64 + k] * LD1<BF>(rw2, k * 64 + tt);
            T2[eg * 64 + tt] = a;
        }
        __syncthreads();
        {
            float mu = 0.f;
            for (int k = 0; k < 64; k++) mu += T2[eg * 64 + k];
            mu *= (1.f / 64.f);
            float var = 0.f;
            for (int k = 0; k < 64; k++) { float d = T2[eg * 64 + k] - mu; var += d * d; }
            float xn = (T2[eg * 64 + tt] - mu) * rsqrtf(var * (1.f / 64.f) + 1e-6f) * LD1<BF>(rl2s, tt) + LD1<BF>(rl2b, tt);
            H2[eg * 64 + tt] = xn * sigmf(xn);
        }
        __syncthreads();
        for (int qq = t; qq < 384; qq += 256) {
            int j0 = qq * 4;
            float4 acc[EPB];
            float4 bv = LD4<BF>(rb3, j0);
            #pragma unroll
            for (int e = 0; e < EPB; e++) acc[e] = bv;
            for (int i = 0; i < 64; i += 8)
                STREAM8_1(rw3, 1536, j0, &H2[e * 64 + i], EPB)
            #pragma unroll
            for (int e = 0; e < EPB; e++) *(float4*)&RAD[e * 1536 + j0] = acc[e];
        }
        __syncthreads();
    }

    // ---- P2: gather + wigner rotate + rad scale (per edge sequential) ----
    {
        float* X  = C;          // 3200
        float* WG = C + 3200;   // 480
        for (int e = 0; e < EPB; e++) {
            int s_ = senders[e0 + e], r_ = receivers[e0 + e];
            for (int q = t; q < 800; q += 256) {
                int k = q >> 5, c0 = (q & 31) * 4;
                float4 v = (c0 < 64) ? LD4<BF>(node_feats, (size_t)s_ * 1600 + k * 64 + c0)
                                     : LD4<BF>(node_feats, (size_t)r_ * 1600 + k * 64 + (c0 - 64));
                *(float4*)&X[q * 4] = v;
            }
            for (int i = t; i < 475; i += 256) WG[i] = LD1<BF>(wigner, (size_t)(e0 + e) * 475 + i);
            __syncthreads();
            for (int q = t; q < 608; q += 256) {
                int m = q >> 5, c0 = (q & 31) * 4;
                float4 acc = make_float4(0.f, 0.f, 0.f, 0.f);
                #pragma unroll
                for (int k = 0; k < 25; k++) fma4(acc, WG[m * 25 + k], *(const float4*)&X[k * 128 + c0]);
                int ri0;
                if (m < 5)       ri0 = m * 128 + c0;
                else if (m < 13) ri0 = 640 + ((m - 5) & 3) * 128 + c0;
                else             ri0 = 1152 + ((m - 13) % 3) * 128 + c0;
                float4 rv = *(const float4*)&RAD[e * 1536 + ri0];
                acc.x *= rv.x; acc.y *= rv.y; acc.z *= rv.z; acc.w *= rv.w;
                *(float4*)&Q[e * 2432 + q * 4] = acc;
            }
            __syncthreads();
        }
    }

    // ---- P3: conv1 (rescheduled: m1 row-split -> combine -> m0 || m2) ----
    float4 ra[EPB], rb[EPB];
    {
        float* EF2 = C;
        float* YM  = YF;  // m1 staging [e][r][512] = 4096 floats
        // stage A: m1 row-split across all 256 threads (512 iters each)
        {
            int r = t >> 7, cg = t & 127;
            int j0 = cg * 4;
            int abase = 640 + 512 * r;
            float4 acc[EPB];
            #pragma unroll
            for (int e = 0; e < EPB; e++) acc[e] = make_float4(0.f, 0.f, 0.f, 0.f);
            for (int i = 0; i < 512; i += 8)
                STREAM8_1(c1w1, 512, j0, &Q[e * 2432 + abase + i], EPB)
            #pragma unroll
            for (int e = 0; e < EPB; e++) *(float4*)&YM[e * 1024 + r * 512 + j0] = acc[e];
        }
        __syncthreads();
        // m1 combine: 1024 units
        for (int u = t; u < 1024; u += 256) {
            int e = u >> 8, j = u & 255;
            float y0l = YM[e * 1024 + j];
            float y0u = YM[e * 1024 + 256 + j];
            float y1l = YM[e * 1024 + 512 + j];
            float y1u = YM[e * 1024 + 768 + j];
            EF2[e * 1216 + 320 + j] = y0l - y1u;
            EF2[e * 1216 + 576 + j] = y1l + y0u;
        }
        __syncthreads();
        // stage B: m0 (t<96) || m2 both-rows (96<=t<192)
        if (t < 96) {
            int jq = (t < 80) ? t : (144 + (t - 80));
            int j0 = jq * 4;
            float4 acc[EPB];
            float4 bv = LD4<BF>(c1b0, j0);
            #pragma unroll
            for (int e = 0; e < EPB; e++) acc[e] = bv;
            for (int i = 0; i < 640; i += 8)
                STREAM8_1(c1w0, 640, j0, &Q[e * 2432 + i], EPB)
            if (t < 80) {
                #pragma unroll
                for (int e = 0; e < EPB; e++) *(float4*)&EF2[e * 1216 + j0] = acc[e];
            } else {
                #pragma unroll
                for (int e = 0; e < EPB; e++) *(float4*)&GAT[e * 64 + (t - 80) * 4] = acc[e];
            }
        } else if (t < 192) {
            int j0 = (t - 96) * 4;  // 0..380
            #pragma unroll
            for (int e = 0; e < EPB; e++) { ra[e] = make_float4(0,0,0,0); rb[e] = make_float4(0,0,0,0); }
            for (int i = 0; i < 384; i += 8)
                STREAM8_2(c1w2, 384, j0, &Q[e * 2432 + 1664 + i], &Q[e * 2432 + 2048 + i])
            if (j0 >= 192) {  // stage upper halves
                #pragma unroll
                for (int e = 0; e < EPB; e++) {
                    *(float4*)&YF[e * 192 + (j0 - 192)] = ra[e];
                    *(float4*)&YF[768 + e * 192 + (j0 - 192)] = rb[e];
                }
            }
        }
        __syncthreads();
        if (t >= 96 && t < 144) {  // m2 combine (j0 < 192)
            int j0 = (t - 96) * 4;
            #pragma unroll
            for (int e = 0; e < EPB; e++) {
                float4 y0u = *(const float4*)&YF[e * 192 + j0];
                float4 y1u = *(const float4*)&YF[768 + e * 192 + j0];
                float4 r, im;
                r.x = ra[e].x - y1u.x; r.y = ra[e].y - y1u.y; r.z = ra[e].z - y1u.z; r.w = ra[e].w - y1u.w;
                im.x = rb[e].x + y0u.x; im.y = rb[e].y + y0u.y; im.z = rb[e].z + y0u.z; im.w = rb[e].w + y0u.w;
                *(float4*)&EF2[e * 1216 + 832 + j0] = r;
                *(float4*)&EF2[e * 1216 + 1024 + j0] = im;
            }
        }
        __syncthreads();
    }

    // ---- P4: grid nonlinearity (full 100-point grid, balanced from_grid) ----
    {
        float* FE  = YF;        // FEATS [e][1216]
        float* G   = Q;         // 100 x 64 = 6400
        float* S2  = Q + 6400;  // 608 f4 = 2432
        float* EF2 = C;
        for (int e = 0; e < EPB; e++) {
            for (int idx = t; idx < 1600; idx += 256) {
                int gi = idx >> 4, c0 = (idx & 15) * 4;
                float4 acc = make_float4(0.f, 0.f, 0.f, 0.f);
                #pragma unroll
                for (int m = 0; m < 19; m++)
                    fma4(acc, LD1<BF>(to_grid, gi * 19 + m),
                         *(const float4*)&EF2[e * 1216 + m * 64 + c0]);
                silu4(acc);
                *(float4*)&G[gi * 64 + c0] = acc;
            }
            __syncthreads();
            for (int idx = t; idx < 608; idx += 256) {
                int m = idx >> 5, cq = (idx >> 1) & 15, h = idx & 1, c0 = cq * 4;
                int g0 = h * 50;
                float4 acc = make_float4(0.f, 0.f, 0.f, 0.f);
                #pragma unroll 5
                for (int gi = 0; gi < 50; gi++)
                    fma4(acc, LD1<BF>(from_grid, (g0 + gi) * 19 + m),
                         *(const float4*)&G[(g0 + gi) * 64 + c0]);
                *(float4*)&S2[idx * 4] = acc;
            }
            __syncthreads();
            for (int idx = t; idx < 304; idx += 256) {
                int m = idx >> 4, cq = idx & 15;
                int pb = (m * 32 + cq * 2) * 4;
                float4 a = *(const float4*)&S2[pb];
                float4 b = *(const float4*)&S2[pb + 4];
                a.x += b.x; a.y += b.y; a.z += b.z; a.w += b.w;
                *(float4*)&FE[e * 1216 + m * 64 + cq * 4] = a;
            }
            __syncthreads();
        }
        if (t < 64) {
            #pragma unroll
            for (int e = 0; e < EPB; e++) { float x = GAT[e * 64 + t]; FE[e * 1216 + t] = x * sigmf(x); }
        }
        __syncthreads();
    }

    // ---- P5: conv2 -> EF3 (in Q; weights shared across 4 edges) ----
    {
        float* FE = YF;
        if (t < 160) {  // m0: 640 outs, k=320
            int j0 = t * 4;
            float4 acc[EPB];
            float4 bv = LD4<BF>(c2b0, j0);
            #pragma unroll
            for (int e = 0; e < EPB; e++) acc[e] = bv;
            for (int i = 0; i < 320; i += 8)
                STREAM8_1(c2w0, 640, j0, &FE[e * 1216 + i], EPB)
            #pragma unroll
            for (int e = 0; e < EPB; e++) *(float4*)&Q[e * 2432 + j0] = acc[e];
        }
        {  // m1: 1024 cols, k=256, all threads, both rows
            int j0 = t * 4;
            #pragma unroll
            for (int e = 0; e < EPB; e++) { ra[e] = make_float4(0,0,0,0); rb[e] = make_float4(0,0,0,0); }
            for (int i = 0; i < 256; i += 8)
                STREAM8_2(c2w1, 1024, j0, &FE[e * 1216 + 320 + i], &FE[e * 1216 + 576 + i])
            if (j0 >= 512) {
                #pragma unroll
                for (int e = 0; e < EPB; e++) {
                    *(float4*)&C[e * 512 + (j0 - 512)] = ra[e];
                    *(float4*)&C[2048 + e * 512 + (j0 - 512)] = rb[e];
                }
            }
        }
        __syncthreads();
        if (t < 128) {  // m1 combine
            int j0 = t * 4;
            #pragma unroll
            for (int e = 0; e < EPB; e++) {
                float4 y0u = *(const float4*)&C[e * 512 + j0];
                float4 y1u = *(const float4*)&C[2048 + e * 512 + j0];
                float4 r, im;
                r.x = ra[e].x - y1u.x; r.y = ra[e].y - y1u.y; r.z = ra[e].z - y1u.z; r.w = ra[e].w - y1u.w;
                im.x = rb[e].x + y0u.x; im.y = rb[e].y + y0u.y; im.z = rb[e].z + y0u.z; im.w = rb[e].w + y0u.w;
                *(float4*)&Q[e * 2432 + 640 + j0] = r;
                *(float4*)&Q[e * 2432 + 1152 + j0] = im;
            }
        }
        __syncthreads();
        if (t < 192) {  // m2: 768 cols, k=192, both rows
            int j0 = t * 4;
            #pragma unroll
            for (int e = 0; e < EPB; e++) { ra[e] = make_float4(0,0,0,0); rb[e] = make_float4(0,0,0,0); }
            for (int i = 0; i < 192; i += 8)
                STREAM8_2(c2w2, 768, j0, &FE[e * 1216 + 832 + i], &FE[e * 1216 + 1024 + i])
            if (j0 >= 384) {
                #pragma unroll
                for (int e = 0; e < EPB; e++) {
                    *(float4*)&C[e * 384 + (j0 - 384)] = ra[e];
                    *(float4*)&C[1536 + e * 384 + (j0 - 384)] = rb[e];
                }
            }
        }
        __syncthreads();
        if (t < 96) {  // m2 combine
            int j0 = t * 4;
            #pragma unroll
            for (int e = 0; e < EPB; e++) {
                float4 y0u = *(const float4*)&C[e * 384 + j0];
                float4 y1u = *(const float4*)&C[1536 + e * 384 + j0];
                float4 r, im;
                r.x = ra[e].x - y1u.x; r.y = ra[e].y - y1u.y; r.z = ra[e].z - y1u.z; r.w = ra[e].w - y1u.w;
                im.x = rb[e].x + y0u.x; im.y = rb[e].y + y0u.y; im.z = rb[e].z + y0u.z; im.w = rb[e].w + y0u.w;
                *(float4*)&Q[e * 2432 + 1664 + j0] = r;
                *(float4*)&Q[e * 2432 + 2048 + j0] = im;
            }
        }
        __syncthreads();
    }

    // ---- P7: wigner_inv rotate + alpha + fused proj (2 k-chunks {13,12}) ----
    {
        float* WV = C;           // [e][480]
        float* EO = C + 1920;    // up to 13*512 = 6656 floats
        if (t < 32) {
            int h = t & 7;
            int ee = e0 + (t >> 3);
            ALs[t] = alpha[(size_t)ee * 8 + h] / (nden[(size_t)receivers[ee] * 8 + h] + 1e-16f);
        }
        for (int i = t; i < 1900; i += 256) {
            int e = i / 475, j = i - e * 475;
            WV[e * 480 + j] = LD1<BF>(wigner_inv, (size_t)(e0 + e) * 475 + j);
        }
        __syncthreads();
        for (int kb = 0; kb < 25; kb += 13) {
            const int nk = (kb == 0) ? 13 : 12;
            for (int u = t; u < nk * 128; u += 256) {
                int e = u & 3, idx = u >> 2;
                int ki = idx >> 5, c0 = (idx & 31) * 4;
                int k = kb + ki;
                float4 acc = make_float4(0.f, 0.f, 0.f, 0.f);
                #pragma unroll
                for (int m = 0; m < 19; m++)
                    fma4(acc, WV[e * 480 + k * 19 + m], *(const float4*)&Q[e * 2432 + m * 128 + c0]);
                float al = ALs[e * 8 + (c0 >> 4)];
                int b = (ki * 128 + c0) * 4 + e;
                EO[b + 0]  = acc.x * al;
                EO[b + 4]  = acc.y * al;
                EO[b + 8]  = acc.z * al;
                EO[b + 12] = acc.w * al;
            }
            __syncthreads();
            if (t < nk * 16) {
                int ki = t >> 4, o0 = (t & 15) * 4;
                int k = kb + ki;
                int l = (k == 0) ? 0 : (k < 4) ? 1 : (k < 9) ? 2 : (k < 16) ? 3 : 4;
                float4 pa0 = make_float4(0,0,0,0), pa1 = pa0, pa2 = pa0, pa3 = pa0;
                const float* eob = &EO[ki * 512];
                size_t base = (size_t)l * 8192 + o0;
                for (int c = 0; c < 128; c += 4) {
                    float4 p0 = LD4<BF>(proj_w, base + (size_t)(c + 0) * 64);
                    float4 p1 = LD4<BF>(proj_w, base + (size_t)(c + 1) * 64);
                    float4 p2 = LD4<BF>(proj_w, base + (size_t)(c + 2) * 64);
                    float4 p3 = LD4<BF>(proj_w, base + (size_t)(c + 3) * 64);
                    float4 v0 = *(const float4*)&eob[(c + 0) * 4];
                    float4 v1 = *(const float4*)&eob[(c + 1) * 4];
                    float4 v2 = *(const float4*)&eob[(c + 2) * 4];
                    float4 v3 = *(const float4*)&eob[(c + 3) * 4];
                    fma4(pa0, v0.x, p0); fma4(pa1, v0.y, p0); fma4(pa2, v0.z, p0); fma4(pa3, v0.w, p0);
                    fma4(pa0, v1.x, p1); fma4(pa1, v1.y, p1); fma4(pa2, v1.z, p1); fma4(pa3, v1.w, p1);
                    fma4(pa0, v2.x, p2); fma4(pa1, v2.y, p2); fma4(pa2, v2.z, p2); fma4(pa3, v2.w, p2);
                    fma4(pa0, v3.x, p3); fma4(pa1, v3.y, p3); fma4(pa2, v3.z, p3); fma4(pa3, v3.w, p3);
                }
                float* d0 = &accb[(size_t)rcv[0] * 1600 + k * 64 + o0];
                atomicAdd(d0 + 0, pa0.x); atomicAdd(d0 + 1, pa0.y);
                atomicAdd(d0 + 2, pa0.z); atomicAdd(d0 + 3, pa0.w);
                float* d1 = &accb[(size_t)rcv[1] * 1600 + k * 64 + o0];
                atomicAdd(d1 + 0, pa1.x); atomicAdd(d1 + 1, pa1.y);
                atomicAdd(d1 + 2, pa1.z); atomicAdd(d1 + 3, pa1.w);
                float* d2 = &accb[(size_t)rcv[2] * 1600 + k * 64 + o0];
                atomicAdd(d2 + 0, pa2.x); atomicAdd(d2 + 1, pa2.y);
                atomicAdd(d2 + 2, pa2.z); atomicAdd(d2 + 3, pa2.w);
                float* d3 = &accb[(size_t)rcv[3] * 1600 + k * 64 + o0];
                atomicAdd(d3 + 0, pa3.x); atomicAdd(d3 + 1, pa3.y);
                atomicAdd(d3 + 2, pa3.z); atomicAdd(d3 + 3, pa3.w);
            }
            __syncthreads();
        }
    }
}

// ---------------- bias + convert ----------------
template<bool BF>
__global__ void k_out(const float* __restrict__ accb, const void* __restrict__ proj_b,
                      void* __restrict__ out, const int* __restrict__ dtf) {
    if ((*dtf != 0) != BF) return;
    int i = blockIdx.x * 256 + threadIdx.x;
    if (i >= NNODES * 1600) return;
    int r = i % 1600;
    int m = r >> 6, o = r & 63;
    float v = accb[i] + ((m == 0) ? LD1<BF>(proj_b, o) : 0.0f);
    if (BF) ((bf16*)out)[i] = __float2bfloat16(v);
    else    ((float*)out)[i] = v;
}

extern "C" void kernel_launch(void* const* d_in, const int* in_sizes, int n_in,
                              void* d_out, int out_size, void* d_ws, size_t ws_size,
                              hipStream_t stream) {
    const void* node_feats = d_in[0];
    const void* edge_dist  = d_in[1];
    const void* wigner     = d_in[2];
    const void* wigner_inv = d_in[3];
    const void* to_grid    = d_in[4];
    const void* from_grid  = d_in[5];
    const void* emb_s      = d_in[6];
    const void* emb_r      = d_in[7];
    const void* rw1  = d_in[8];
    const void* rb1  = d_in[9];
    const void* rl1s = d_in[10];
    const void* rl1b = d_in[11];
    const void* rw2  = d_in[12];
    const void* rb2  = d_in[13];
    const void* rl2s = d_in[14];
    const void* rl2b = d_in[15];
    const void* rw3  = d_in[16];
    const void* rb3  = d_in[17];
    const void* c1w0 = d_in[18];
    const void* c1b0 = d_in[19];
    const void* c1w1 = d_in[20];
    const void* c1w2 = d_in[21];
    const void* c2w0 = d_in[22];
    const void* c2b0 = d_in[23];
    const void* c2w1 = d_in[24];
    const void* c2w2 = d_in[25];
    const void* an_s = d_in[26];
    const void* an_b = d_in[27];
    const void* adot = d_in[28];
    const void* proj_w = d_in[29];
    const void* proj_b = d_in[30];
    const int* species   = (const int*)d_in[31];
    const int* senders   = (const int*)d_in[32];
    const int* receivers = (const int*)d_in[33];

    char* ws = (char*)d_ws;
    float*    accb  = (float*)ws;                   // 32,000,000 B
    float*    alpha = (float*)(ws + 32000000);      // 800,000 B
    unsigned* nmax  = (unsigned*)(ws + 32800000);   // 160,000 B
    float*    nden  = (float*)(ws + 32960000);      // 160,000 B
    int*      dtf   = (int*)(ws + 33120000);        // 4 B

    k_detect<<<1, 64, 0, stream>>>(edge_dist, dtf);
    k_fill<<<(NNODES * 1600 + 255) / 256, 256, 0, stream>>>(accb, nden, nmax);

    k_alpha<true><<<NBLK, 256, 0, stream>>>(
        node_feats, edge_dist, wigner, emb_s, emb_r,
        rw1, rb1, rl1s, rl1b, rw2, rb2, rl2s, rl2b, rw3, rb3,
        c1w0, c1b0, an_s, an_b, adot, species, senders, receivers, dtf,
        alpha, nmax);
    k_alpha<false><<<NBLK, 256, 0, stream>>>(
        node_feats, edge_dist, wigner, emb_s, emb_r,
        rw1, rb1, rl1s, rl1b, rw2, rb2, rl2s, rl2b, rw3, rb3,
        c1w0, c1b0, an_s, an_b, adot, species, senders, receivers, dtf,
        alpha, nmax);

    k_exp<<<(EDGES * 8 + 255) / 256, 256, 0, stream>>>(receivers, nmax, alpha, nden);

    k_mega2<true><<<NBLK, 256, 0, stream>>>(
        node_feats, edge_dist, wigner, wigner_inv, to_grid, from_grid, emb_s, emb_r,
        rw1, rb1, rl1s, rl1b, rw2, rb2, rl2s, rl2b, rw3, rb3,
        c1w0, c1b0, c1w1, c1w2, c2w0, c2b0, c2w1, c2w2, proj_w,
        species, senders, receivers, dtf, alpha, nden, accb);
    k_mega2<false><<<NBLK, 256, 0, stream>>>(
        node_feats, edge_dist, wigner, wigner_inv, to_grid, from_grid, emb_s, emb_r,
        rw1, rb1, rl1s, rl1b, rw2, rb2, rl2s, rl2b, rw3, rb3,
        c1w0, c1b0, c1w1, c1w2, c2w0, c2b0, c2w1, c2w2, proj_w,
        species, senders, receivers, dtf, alpha, nden, accb);

    k_out<true><<<(NNODES * 1600 + 255) / 256, 256, 0, stream>>>(accb, proj_b, d_out, dtf);
    k_out<false><<<(NNODES * 1600 + 255) / 256, 256, 0, stream>>>(accb, proj_b, d_out, dtf);
}

// Round 4
// 4748.026 us; speedup vs baseline: 1.1053x; 1.1053x over previous
//
#include <hip/hip_runtime.h>
#include <hip/hip_bf16.h>

using bf16 = __hip_bfloat16;

#define EDGES 25000
#define NNODES 5000
#define EPB 4
#define NBLK (EDGES / EPB)

__device__ __forceinline__ float sigmf(float x) { return 1.0f / (1.0f + expf(-x)); }

template<bool BF>
__device__ __forceinline__ float LD1(const void* p, size_t i) {
    if (BF) return __bfloat162float(((const bf16*)p)[i]);
    else    return ((const float*)p)[i];
}

template<bool BF>
__device__ __forceinline__ float4 LD4(const void* p, size_t i) {
    if (BF) {
        ushort4 u = *reinterpret_cast<const ushort4*>((const bf16*)p + i);
        float4 r;
        r.x = __uint_as_float((unsigned)u.x << 16);
        r.y = __uint_as_float((unsigned)u.y << 16);
        r.z = __uint_as_float((unsigned)u.z << 16);
        r.w = __uint_as_float((unsigned)u.w << 16);
        return r;
    } else {
        return *reinterpret_cast<const float4*>((const float*)p + i);
    }
}

__device__ __forceinline__ void fma4(float4& a, float s, const float4& w) {
    a.x += s * w.x; a.y += s * w.y; a.z += s * w.z; a.w += s * w.w;
}

__device__ __forceinline__ void silu4(float4& a) {
    a.x *= sigmf(a.x); a.y *= sigmf(a.y); a.z *= sigmf(a.z); a.w *= sigmf(a.w);
}

// monotone float<->uint encoding for atomicMax on floats
__device__ __forceinline__ unsigned encF(float f) {
    unsigned b = __float_as_uint(f);
    return (b & 0x80000000u) ? ~b : (b | 0x80000000u);
}
__device__ __forceinline__ float decF(unsigned e) {
    unsigned b = (e & 0x80000000u) ? (e ^ 0x80000000u) : ~e;
    return __uint_as_float(b);
}
#define ENC_NEGINF 0x007FFFFFu

// 4-deep pipelined single-row MAC: acc[e] += act[e][i..i+3] * W[i..i+3][j0..j0+3]
// (depth 8 spilled at VGPR=128 -> scratch round-trips; depth 4 fits)
#define STREAM4_1(Wptr, LDW, j0, ACTEXPR, NACC) \
    { \
        float4 w0 = LD4<BF>(Wptr, (size_t)(i + 0) * (LDW) + (j0)); \
        float4 w1 = LD4<BF>(Wptr, (size_t)(i + 1) * (LDW) + (j0)); \
        float4 w2 = LD4<BF>(Wptr, (size_t)(i + 2) * (LDW) + (j0)); \
        float4 w3 = LD4<BF>(Wptr, (size_t)(i + 3) * (LDW) + (j0)); \
        _Pragma("unroll") \
        for (int e = 0; e < NACC; e++) { \
            const float* qa = ACTEXPR; \
            float4 a0 = *(const float4*)qa; \
            fma4(acc[e], a0.x, w0); fma4(acc[e], a0.y, w1); \
            fma4(acc[e], a0.z, w2); fma4(acc[e], a0.w, w3); \
        } \
    }

// 4-deep pipelined two-row MAC into ra[e], rb[e]
#define STREAM4_2(Wptr, LDW, j0, ACTA, ACTB) \
    { \
        float4 w0 = LD4<BF>(Wptr, (size_t)(i + 0) * (LDW) + (j0)); \
        float4 w1 = LD4<BF>(Wptr, (size_t)(i + 1) * (LDW) + (j0)); \
        float4 w2 = LD4<BF>(Wptr, (size_t)(i + 2) * (LDW) + (j0)); \
        float4 w3 = LD4<BF>(Wptr, (size_t)(i + 3) * (LDW) + (j0)); \
        _Pragma("unroll") \
        for (int e = 0; e < EPB; e++) { \
            const float* pa = ACTA; \
            const float* pb = ACTB; \
            float4 a0 = *(const float4*)pa; \
            float4 b0 = *(const float4*)pb; \
            fma4(ra[e], a0.x, w0); fma4(ra[e], a0.y, w1); \
            fma4(ra[e], a0.z, w2); fma4(ra[e], a0.w, w3); \
            fma4(rb[e], b0.x, w0); fma4(rb[e], b0.y, w1); \
            fma4(rb[e], b0.z, w2); fma4(rb[e], b0.w, w3); \
        } \
    }

// ---------------- dtype detector ----------------
__global__ void k_detect(const void* edge_dist, int* flag) {
    if (threadIdx.x == 0 && blockIdx.x == 0) {
        const bf16* p = (const bf16*)edge_dist;
        int ok = 1;
        for (int i = 0; i < 256; i++) {
            float v = __bfloat162float(p[i]);
            if (!(v >= 0.0f && v <= 1.0f)) { ok = 0; break; }
        }
        *flag = ok;
    }
}

// ---------------- fill ----------------
__global__ void k_fill(float* accb, float* nden, unsigned* nmax) {
    int tid = blockIdx.x * 256 + threadIdx.x;
    if (tid < NNODES * 1600) accb[tid] = 0.0f;
    if (tid < NNODES * 8) { nden[tid] = 0.0f; nmax[tid] = ENC_NEGINF; }
}

// ---------------- alpha prepass: EPB=4, shared weights ----------------
// LDS floats: XE[768]@0 T1@768 H1@1024 T2@1280 H2@1536
// rad0[2560]@1792 x0[2560]@4352 R[4224]@6912 (X=R, WG=R+3200 | Y=R)
// extraA[1024]@11136 -> total 12160 floats = 48640 B -> 3 blocks/CU
template<bool BF>
__global__ __launch_bounds__(256, 3) void k_alpha(
    const void* __restrict__ node_feats, const void* __restrict__ edge_dist,
    const void* __restrict__ wigner, const void* __restrict__ emb_s,
    const void* __restrict__ emb_r,
    const void* __restrict__ rw1, const void* __restrict__ rb1,
    const void* __restrict__ rl1s, const void* __restrict__ rl1b,
    const void* __restrict__ rw2, const void* __restrict__ rb2,
    const void* __restrict__ rl2s, const void* __restrict__ rl2b,
    const void* __restrict__ rw3, const void* __restrict__ rb3,
    const void* __restrict__ c1w0, const void* __restrict__ c1b0,
    const void* __restrict__ an_s, const void* __restrict__ an_b,
    const void* __restrict__ adot,
    const int* __restrict__ species, const int* __restrict__ senders,
    const int* __restrict__ receivers, const int* __restrict__ dtf,
    float* __restrict__ alpha_out, unsigned* __restrict__ nmax)
{
    if ((*dtf != 0) != BF) return;
    __shared__ __align__(16) float sm[12160];
    float* XE   = sm;
    float* T1   = sm + 768;
    float* H1   = sm + 1024;
    float* T2   = sm + 1280;
    float* H2   = sm + 1536;
    float* rad0 = sm + 1792;
    float* x0   = sm + 4352;
    float* R    = sm + 6912;
    float* extraA = sm + 11136;

    const int t = threadIdx.x;
    const int e0 = blockIdx.x * EPB;
    const int eg = t >> 6, tt = t & 63;

    // ---- XE gather (edge-parallel) ----
    {
        int ee = e0 + eg;
        XE[eg * 192 + tt]       = LD1<BF>(edge_dist, (size_t)ee * 64 + tt);
        XE[eg * 192 + 64 + tt]  = LD1<BF>(emb_s, (size_t)species[senders[ee]] * 64 + tt);
        XE[eg * 192 + 128 + tt] = LD1<BF>(emb_r, (size_t)species[receivers[ee]] * 64 + tt);
    }
    __syncthreads();
    // ---- radial MLP (edge-parallel: 64 threads per edge) ----
    {
        float a = LD1<BF>(rb1, tt);
        #pragma unroll 4
        for (int k = 0; k < 192; k++) a += XE[eg * 192 + k] * LD1<BF>(rw1, k * 64 + tt);
        T1[eg * 64 + tt] = a;
    }
    __syncthreads();
    {
        float mu = 0.f;
        for (int k = 0; k < 64; k++) mu += T1[eg * 64 + k];
        mu *= (1.f / 64.f);
        float var = 0.f;
        for (int k = 0; k < 64; k++) { float d = T1[eg * 64 + k] - mu; var += d * d; }
        float xn = (T1[eg * 64 + tt] - mu) * rsqrtf(var * (1.f / 64.f) + 1e-6f) * LD1<BF>(rl1s, tt) + LD1<BF>(rl1b, tt);
        H1[eg * 64 + tt] = xn * sigmf(xn);
    }
    __syncthreads();
    {
        float a = LD1<BF>(rb2, tt);
        #pragma unroll 4
        for (int k = 0; k < 64; k++) a += H1[eg * 64 + k] * LD1<BF>(rw2, k * 64 + tt);
        T2[eg * 64 + tt] = a;
    }
    __syncthreads();
    {
        float mu = 0.f;
        for (int k = 0; k < 64; k++) mu += T2[eg * 64 + k];
        mu *= (1.f / 64.f);
        float var = 0.f;
        for (int k = 0; k < 64; k++) { float d = T2[eg * 64 + k] - mu; var += d * d; }
        float xn = (T2[eg * 64 + tt] - mu) * rsqrtf(var * (1.f / 64.f) + 1e-6f) * LD1<BF>(rl2s, tt) + LD1<BF>(rl2b, tt);
        H2[eg * 64 + tt] = xn * sigmf(xn);
    }
    __syncthreads();
    // ---- rad0: first 640 outputs of rad, weights shared across 4 edges ----
    if (t < 160) {
        int j0 = t * 4;
        float4 acc[EPB];
        float4 bv = LD4<BF>(rb3, j0);
        #pragma unroll
        for (int e = 0; e < EPB; e++) acc[e] = bv;
        for (int i = 0; i < 64; i += 4)
            STREAM4_1(rw3, 1536, j0, &H2[e * 64 + i], EPB)
        #pragma unroll
        for (int e = 0; e < EPB; e++) *(float4*)&rad0[e * 640 + j0] = acc[e];
    }
    __syncthreads();
    // ---- per-edge: X gather + rotate rows 0..4 + rad scale ----
    {
        float* X  = R;
        float* WG = R + 3200;
        for (int e = 0; e < EPB; e++) {
            int s_ = senders[e0 + e], r_ = receivers[e0 + e];
            for (int q = t; q < 800; q += 256) {
                int k = q >> 5, c0 = (q & 31) * 4;
                float4 v = (c0 < 64) ? LD4<BF>(node_feats, (size_t)s_ * 1600 + k * 64 + c0)
                                     : LD4<BF>(node_feats, (size_t)r_ * 1600 + k * 64 + (c0 - 64));
                *(float4*)&X[q * 4] = v;
            }
            for (int i = t; i < 125; i += 256) WG[i] = LD1<BF>(wigner, (size_t)(e0 + e) * 475 + i);
            __syncthreads();
            if (t < 160) {
                int m = t >> 5, c0 = (t & 31) * 4;
                float4 acc = make_float4(0.f, 0.f, 0.f, 0.f);
                #pragma unroll
                for (int k = 0; k < 25; k++) fma4(acc, WG[m * 25 + k], *(const float4*)&X[k * 128 + c0]);
                float4 rv = *(const float4*)&rad0[e * 640 + t * 4];
                acc.x *= rv.x; acc.y *= rv.y; acc.z *= rv.z; acc.w *= rv.w;
                *(float4*)&x0[e * 640 + t * 4] = acc;
            }
            __syncthreads();
        }
    }
    // ---- alpha matmul: cols [320,576), k split 4 ways, weights shared ----
    {
        float* Y = R;
        int col = t & 63, kq = t >> 6;
        int j0 = 320 + col * 4;
        int ibase = kq * 160;
        float4 acc[EPB];
        #pragma unroll
        for (int e = 0; e < EPB; e++) acc[e] = make_float4(0.f, 0.f, 0.f, 0.f);
        for (int i = ibase; i < ibase + 160; i += 4)
            STREAM4_1(c1w0, 640, j0, &x0[e * 640 + i], EPB)
        __syncthreads();  // R (X/WG) dead; Y overlays
        #pragma unroll
        for (int e = 0; e < EPB; e++) *(float4*)&Y[(e * 256 + kq * 64 + col) * 4] = acc[e];
        __syncthreads();
        {
            int e = t >> 6, c = t & 63;
            float4 s = LD4<BF>(c1b0, 320 + c * 4);
            #pragma unroll
            for (int q = 0; q < 4; q++) {
                float4 v = *(const float4*)&Y[(e * 256 + q * 64 + c) * 4];
                s.x += v.x; s.y += v.y; s.z += v.z; s.w += v.w;
            }
            *(float4*)&extraA[e * 256 + c * 4] = s;
        }
    }
    __syncthreads();
    if (t < 32) {
        int e = t >> 3, h = t & 7;
        float mu = 0.0f;
        for (int k = 0; k < 32; k++) mu += extraA[e * 256 + h * 32 + k];
        mu *= (1.0f / 32.0f);
        float var = 0.0f;
        for (int k = 0; k < 32; k++) { float d = extraA[e * 256 + h * 32 + k] - mu; var += d * d; }
        float rs = rsqrtf(var * (1.0f / 32.0f) + 1e-6f);
        float logit = 0.0f;
        for (int k = 0; k < 32; k++) {
            float xn = (extraA[e * 256 + h * 32 + k] - mu) * rs * LD1<BF>(an_s, k) + LD1<BF>(an_b, k);
            float slr = 0.6f * xn + 0.4f * xn * (2.0f * sigmf(xn) - 1.0f);
            logit += slr * LD1<BF>(adot, h * 32 + k);
        }
        int r = receivers[e0 + e];
        alpha_out[(size_t)(e0 + e) * 8 + h] = logit;
        atomicMax(&nmax[r * 8 + h], encF(logit));
    }
}

// ---------------- exp + denom ----------------
__global__ void k_exp(const int* __restrict__ receivers, const unsigned* __restrict__ nmax,
                      float* __restrict__ alpha, float* __restrict__ nden) {
    int tid = blockIdx.x * 256 + threadIdx.x;
    if (tid >= EDGES * 8) return;
    int e = tid >> 3, h = tid & 7;
    int r = receivers[e];
    float m = decF(nmax[r * 8 + h]);
    float ex = expf(alpha[tid] - m);
    alpha[tid] = ex;
    atomicAdd(&nden[r * 8 + h], ex);
}

// ---------------- mega2: 4 edges per block ----------------
// LDS map (floats, total 19744 = 77.1 KB -> 2 blocks/CU):
//   Q   [0,9728)      : EF1[e][2432] (P2-P3) | G(6400)+S2(2432) (P4) | EF3[e][2432] (P5-P7)
//   C   [9728,14592)  : P1 scratch | P2 X+wg | EF2[e][1216] (P3-P4) | P5 staging | P7 WV+EO
//   RAD [13408,19552) : radial out [e][1536] (live P1-P2 only)
//   YF  [14592,19456) : P3 m1 row-split staging (4096) + m2 staging | FEATS (P4-P5) | P7 EO tail
//   GAT [19456,19712) : gating [e][64] (P3-P4)
//   ALs [19712,19744) : alpha scale [e][8] (P7)
template<bool BF>
__global__ __launch_bounds__(256, 2) void k_mega2(
    const void* __restrict__ node_feats, const void* __restrict__ edge_dist,
    const void* __restrict__ wigner, const void* __restrict__ wigner_inv,
    const void* __restrict__ to_grid, const void* __restrict__ from_grid,
    const void* __restrict__ emb_s, const void* __restrict__ emb_r,
    const void* __restrict__ rw1, const void* __restrict__ rb1,
    const void* __restrict__ rl1s, const void* __restrict__ rl1b,
    const void* __restrict__ rw2, const void* __restrict__ rb2,
    const void* __restrict__ rl2s, const void* __restrict__ rl2b,
    const void* __restrict__ rw3, const void* __restrict__ rb3,
    const void* __restrict__ c1w0, const void* __restrict__ c1b0,
    const void* __restrict__ c1w1, const void* __restrict__ c1w2,
    const void* __restrict__ c2w0, const void* __restrict__ c2b0,
    const void* __restrict__ c2w1, const void* __restrict__ c2w2,
    const void* __restrict__ proj_w,
    const int* __restrict__ species, const int* __restrict__ senders,
    const int* __restrict__ receivers, const int* __restrict__ dtf,
    const float* __restrict__ alpha, const float* __restrict__ nden,
    float* __restrict__ accb)
{
    if ((*dtf != 0) != BF) return;
    __shared__ __align__(16) float sm[19744];
    float* Q   = sm;
    float* C   = sm + 9728;
    float* RAD = sm + 13408;
    float* YF  = sm + 14592;
    float* GAT = sm + 19456;
    float* ALs = sm + 19712;

    const int t = threadIdx.x;
    const int e0 = blockIdx.x * EPB;
    int snd[EPB], rcv[EPB];
    #pragma unroll
    for (int e = 0; e < EPB; e++) { snd[e] = senders[e0 + e]; rcv[e] = receivers[e0 + e]; }

    // ---- P1: radial MLP (edge-parallel 4x64; rw3 weights shared) ----
    {
        float* XE = C;
        float* T1 = C + 768;
        float* H1 = C + 1024;
        float* T2 = C + 1280;
        float* H2 = C + 1536;
        const int eg = t >> 6, tt = t & 63;
        {
            int ee = e0 + eg;
            XE[eg * 192 + tt]       = LD1<BF>(edge_dist, (size_t)ee * 64 + tt);
            XE[eg * 192 + 64 + tt]  = LD1<BF>(emb_s, (size_t)species[senders[ee]] * 64 + tt);
            XE[eg * 192 + 128 + tt] = LD1<BF>(emb_r, (size_t)species[receivers[ee]] * 64 + tt);
        }
        __syncthreads();
        {
            float a = LD1<BF>(rb1, tt);
            #pragma unroll 4
            for (int k = 0; k < 192; k++) a += XE[eg * 192 + k] * LD1<BF>(rw1, k * 64 + tt);
            T1[eg * 64 + tt] = a;
        }
        __syncthreads();
        {
            float mu = 0.f;
            for (int k = 0; k < 64; k++) mu += T1[eg * 64 + k];
            mu *= (1.f / 64.f);
            float var = 0.f;
            for (int k = 0; k < 64; k++) { float d = T1[eg * 64 + k] - mu; var += d * d; }
            float xn = (T1[eg * 64 + tt] - mu) * rsqrtf(var * (1.f / 64.f) + 1e-6f) * LD1<BF>(rl1s, tt) + LD1<BF>(rl1b, tt);
            H1[eg * 64 + tt] = xn * sigmf(xn);
        }
        __syncthreads();
        {
            float a = LD1<BF>(rb2, tt);
            #pragma unroll 4
            for (int k = 0; k < 64; k++) a += H1[eg * 64 + k] * LD1<BF>(rw2, k * 64 + tt);
            T2[eg * 64 + tt] = a;
        }
        __syncthreads();
        {
            float mu = 0.f;
            for (int k = 0; k < 64; k++) mu += T2[eg * 64 + k];
            mu *= (1.f / 64.f);
            float var = 0.f;
            for (int k = 0; k < 64; k++) { float d = T2[eg * 64 + k] - mu; var += d * d; }
            float xn = (T2[eg * 64 + tt] - mu) * rsqrtf(var * (1.f / 64.f) + 1e-6f) * LD1<BF>(rl2s, tt) + LD1<BF>(rl2b, tt);
            H2[eg * 64 + tt] = xn * sigmf(xn);
        }
        __syncthreads();
        for (int qq = t; qq < 384; qq += 256) {
            int j0 = qq * 4;
            float4 acc[EPB];
            float4 bv = LD4<BF>(rb3, j0);
            #pragma unroll
            for (int e = 0; e < EPB; e++) acc[e] = bv;
            for (int i = 0; i < 64; i += 4)
                STREAM4_1(rw3, 1536, j0, &H2[e * 64 + i], EPB)
            #pragma unroll
            for (int e = 0; e < EPB; e++) *(float4*)&RAD[e * 1536 + j0] = acc[e];
        }
        __syncthreads();
    }

    // ---- P2: gather + wigner rotate + rad scale (per edge sequential) ----
    {
        float* X  = C;          // 3200
        float* WG = C + 3200;   // 480
        for (int e = 0; e < EPB; e++) {
            int s_ = senders[e0 + e], r_ = receivers[e0 + e];
            for (int q = t; q < 800; q += 256) {
                int k = q >> 5, c0 = (q & 31) * 4;
                float4 v = (c0 < 64) ? LD4<BF>(node_feats, (size_t)s_ * 1600 + k * 64 + c0)
                                     : LD4<BF>(node_feats, (size_t)r_ * 1600 + k * 64 + (c0 - 64));
                *(float4*)&X[q * 4] = v;
            }
            for (int i = t; i < 475; i += 256) WG[i] = LD1<BF>(wigner, (size_t)(e0 + e) * 475 + i);
            __syncthreads();
            for (int q = t; q < 608; q += 256) {
                int m = q >> 5, c0 = (q & 31) * 4;
                float4 acc = make_float4(0.f, 0.f, 0.f, 0.f);
                #pragma unroll
                for (int k = 0; k < 25; k++) fma4(acc, WG[m * 25 + k], *(const float4*)&X[k * 128 + c0]);
                int ri0;
                if (m < 5)       ri0 = m * 128 + c0;
                else if (m < 13) ri0 = 640 + ((m - 5) & 3) * 128 + c0;
                else             ri0 = 1152 + ((m - 13) % 3) * 128 + c0;
                float4 rv = *(const float4*)&RAD[e * 1536 + ri0];
                acc.x *= rv.x; acc.y *= rv.y; acc.z *= rv.z; acc.w *= rv.w;
                *(float4*)&Q[e * 2432 + q * 4] = acc;
            }
            __syncthreads();
        }
    }

    // ---- P3: conv1 (m1 row-split -> combine -> m0 || m2) ----
    float4 ra[EPB], rb[EPB];
    {
        float* EF2 = C;
        float* YM  = YF;  // m1 staging [e][r][512] = 4096 floats
        // stage A: m1 row-split across all 256 threads
        {
            int r = t >> 7, cg = t & 127;
            int j0 = cg * 4;
            int abase = 640 + 512 * r;
            float4 acc[EPB];
            #pragma unroll
            for (int e = 0; e < EPB; e++) acc[e] = make_float4(0.f, 0.f, 0.f, 0.f);
            for (int i = 0; i < 512; i += 4)
                STREAM4_1(c1w1, 512, j0, &Q[e * 2432 + abase + i], EPB)
            #pragma unroll
            for (int e = 0; e < EPB; e++) *(float4*)&YM[e * 1024 + r * 512 + j0] = acc[e];
        }
        __syncthreads();
        // m1 combine: 1024 units
        for (int u = t; u < 1024; u += 256) {
            int e = u >> 8, j = u & 255;
            float y0l = YM[e * 1024 + j];
            float y0u = YM[e * 1024 + 256 + j];
            float y1l = YM[e * 1024 + 512 + j];
            float y1u = YM[e * 1024 + 768 + j];
            EF2[e * 1216 + 320 + j] = y0l - y1u;
            EF2[e * 1216 + 576 + j] = y1l + y0u;
        }
        __syncthreads();
        // stage B: m0 (t<96) || m2 both-rows (96<=t<192)
        if (t < 96) {
            int jq = (t < 80) ? t : (144 + (t - 80));
            int j0 = jq * 4;
            float4 acc[EPB];
            float4 bv = LD4<BF>(c1b0, j0);
            #pragma unroll
            for (int e = 0; e < EPB; e++) acc[e] = bv;
            for (int i = 0; i < 640; i += 4)
                STREAM4_1(c1w0, 640, j0, &Q[e * 2432 + i], EPB)
            if (t < 80) {
                #pragma unroll
                for (int e = 0; e < EPB; e++) *(float4*)&EF2[e * 1216 + j0] = acc[e];
            } else {
                #pragma unroll
                for (int e = 0; e < EPB; e++) *(float4*)&GAT[e * 64 + (t - 80) * 4] = acc[e];
            }
        } else if (t < 192) {
            int j0 = (t - 96) * 4;  // 0..380
            #pragma unroll
            for (int e = 0; e < EPB; e++) { ra[e] = make_float4(0,0,0,0); rb[e] = make_float4(0,0,0,0); }
            for (int i = 0; i < 384; i += 4)
                STREAM4_2(c1w2, 384, j0, &Q[e * 2432 + 1664 + i], &Q[e * 2432 + 2048 + i])
            if (j0 >= 192) {  // stage upper halves
                #pragma unroll
                for (int e = 0; e < EPB; e++) {
                    *(float4*)&YF[e * 192 + (j0 - 192)] = ra[e];
                    *(float4*)&YF[768 + e * 192 + (j0 - 192)] = rb[e];
                }
            }
        }
        __syncthreads();
        if (t >= 96 && t < 144) {  // m2 combine (j0 < 192)
            int j0 = (t - 96) * 4;
            #pragma unroll
            for (int e = 0; e < EPB; e++) {
                float4 y0u = *(const float4*)&YF[e * 192 + j0];
                float4 y1u = *(const float4*)&YF[768 + e * 192 + j0];
                float4 r, im;
                r.x = ra[e].x - y1u.x; r.y = ra[e].y - y1u.y; r.z = ra[e].z - y1u.z; r.w = ra[e].w - y1u.w;
                im.x = rb[e].x + y0u.x; im.y = rb[e].y + y0u.y; im.z = rb[e].z + y0u.z; im.w = rb[e].w + y0u.w;
                *(float4*)&EF2[e * 1216 + 832 + j0] = r;
                *(float4*)&EF2[e * 1216 + 1024 + j0] = im;
            }
        }
        __syncthreads();
    }

    // ---- P4: grid nonlinearity (full 100-point grid, balanced from_grid) ----
    {
        float* FE  = YF;        // FEATS [e][1216]
        float* G   = Q;         // 100 x 64 = 6400
        float* S2  = Q + 6400;  // 608 f4 = 2432
        float* EF2 = C;
        for (int e = 0; e < EPB; e++) {
            for (int idx = t; idx < 1600; idx += 256) {
                int gi = idx >> 4, c0 = (idx & 15) * 4;
                float4 acc = make_float4(0.f, 0.f, 0.f, 0.f);
                #pragma unroll
                for (int m = 0; m < 19; m++)
                    fma4(acc, LD1<BF>(to_grid, gi * 19 + m),
                         *(const float4*)&EF2[e * 1216 + m * 64 + c0]);
                silu4(acc);
                *(float4*)&G[gi * 64 + c0] = acc;
            }
            __syncthreads();
            for (int idx = t; idx < 608; idx += 256) {
                int m = idx >> 5, cq = (idx >> 1) & 15, h = idx & 1, c0 = cq * 4;
                int g0 = h * 50;
                float4 acc = make_float4(0.f, 0.f, 0.f, 0.f);
                #pragma unroll 5
                for (int gi = 0; gi < 50; gi++)
                    fma4(acc, LD1<BF>(from_grid, (g0 + gi) * 19 + m),
                         *(const float4*)&G[(g0 + gi) * 64 + c0]);
                *(float4*)&S2[idx * 4] = acc;
            }
            __syncthreads();
            for (int idx = t; idx < 304; idx += 256) {
                int m = idx >> 4, cq = idx & 15;
                int pb = (m * 32 + cq * 2) * 4;
                float4 a = *(const float4*)&S2[pb];
                float4 b = *(const float4*)&S2[pb + 4];
                a.x += b.x; a.y += b.y; a.z += b.z; a.w += b.w;
                *(float4*)&FE[e * 1216 + m * 64 + cq * 4] = a;
            }
            __syncthreads();
        }
        if (t < 64) {
            #pragma unroll
            for (int e = 0; e < EPB; e++) { float x = GAT[e * 64 + t]; FE[e * 1216 + t] = x * sigmf(x); }
        }
        __syncthreads();
    }

    // ---- P5: conv2 -> EF3 (in Q; weights shared across 4 edges) ----
    {
        float* FE = YF;
        if (t < 160) {  // m0: 640 outs, k=320
            int j0 = t * 4;
            float4 acc[EPB];
            float4 bv = LD4<BF>(c2b0, j0);
            #pragma unroll
            for (int e = 0; e < EPB; e++) acc[e] = bv;
            for (int i = 0; i < 320; i += 4)
                STREAM4_1(c2w0, 640, j0, &FE[e * 1216 + i], EPB)
            #pragma unroll
            for (int e = 0; e < EPB; e++) *(float4*)&Q[e * 2432 + j0] = acc[e];
        }
        {  // m1: 1024 cols, k=256, all threads, both rows
            int j0 = t * 4;
            #pragma unroll
            for (int e = 0; e < EPB; e++) { ra[e] = make_float4(0,0,0,0); rb[e] = make_float4(0,0,0,0); }
            for (int i = 0; i < 256; i += 4)
                STREAM4_2(c2w1, 1024, j0, &FE[e * 1216 + 320 + i], &FE[e * 1216 + 576 + i])
            if (j0 >= 512) {
                #pragma unroll
                for (int e = 0; e < EPB; e++) {
                    *(float4*)&C[e * 512 + (j0 - 512)] = ra[e];
                    *(float4*)&C[2048 + e * 512 + (j0 - 512)] = rb[e];
                }
            }
        }
        __syncthreads();
        if (t < 128) {  // m1 combine
            int j0 = t * 4;
            #pragma unroll
            for (int e = 0; e < EPB; e++) {
                float4 y0u = *(const float4*)&C[e * 512 + j0];
                float4 y1u = *(const float4*)&C[2048 + e * 512 + j0];
                float4 r, im;
                r.x = ra[e].x - y1u.x; r.y = ra[e].y - y1u.y; r.z = ra[e].z - y1u.z; r.w = ra[e].w - y1u.w;
                im.x = rb[e].x + y0u.x; im.y = rb[e].y + y0u.y; im.z = rb[e].z + y0u.z; im.w = rb[e].w + y0u.w;
                *(float4*)&Q[e * 2432 + 640 + j0] = r;
                *(float4*)&Q[e * 2432 + 1152 + j0] = im;
            }
        }
        __syncthreads();
        if (t < 192) {  // m2: 768 cols, k=192, both rows
            int j0 = t * 4;
            #pragma unroll
            for (int e = 0; e < EPB; e++) { ra[e] = make_float4(0,0,0,0); rb[e] = make_float4(0,0,0,0); }
            for (int i = 0; i < 192; i += 4)
                STREAM4_2(c2w2, 768, j0, &FE[e * 1216 + 832 + i], &FE[e * 1216 + 1024 + i])
            if (j0 >= 384) {
                #pragma unroll
                for (int e = 0; e < EPB; e++) {
                    *(float4*)&C[e * 384 + (j0 - 384)] = ra[e];
                    *(float4*)&C[1536 + e * 384 + (j0 - 384)] = rb[e];
                }
            }
        }
        __syncthreads();
        if (t < 96) {  // m2 combine
            int j0 = t * 4;
            #pragma unroll
            for (int e = 0; e < EPB; e++) {
                float4 y0u = *(const float4*)&C[e * 384 + j0];
                float4 y1u = *(const float4*)&C[1536 + e * 384 + j0];
                float4 r, im;
                r.x = ra[e].x - y1u.x; r.y = ra[e].y - y1u.y; r.z = ra[e].z - y1u.z; r.w = ra[e].w - y1u.w;
                im.x = rb[e].x + y0u.x; im.y = rb[e].y + y0u.y; im.z = rb[e].z + y0u.z; im.w = rb[e].w + y0u.w;
                *(float4*)&Q[e * 2432 + 1664 + j0] = r;
                *(float4*)&Q[e * 2432 + 2048 + j0] = im;
            }
        }
        __syncthreads();
    }

    // ---- P7: wigner_inv rotate + alpha + fused proj (2 k-chunks {13,12}) ----
    {
        float* WV = C;           // [e][480]
        float* EO = C + 1920;    // up to 13*512 = 6656 floats
        if (t < 32) {
            int h = t & 7;
            int ee = e0 + (t >> 3);
            ALs[t] = alpha[(size_t)ee * 8 + h] / (nden[(size_t)receivers[ee] * 8 + h] + 1e-16f);
        }
        for (int i = t; i < 1900; i += 256) {
            int e = i / 475, j = i - e * 475;
            WV[e * 480 + j] = LD1<BF>(wigner_inv, (size_t)(e0 + e) * 475 + j);
        }
        __syncthreads();
        for (int kb = 0; kb < 25; kb += 13) {
            const int nk = (kb == 0) ? 13 : 12;
            for (int u = t; u < nk * 128; u += 256) {
                int e = u & 3, idx = u >> 2;
                int ki = idx >> 5, c0 = (idx & 31) * 4;
                int k = kb + ki;
                float4 acc = make_float4(0.f, 0.f, 0.f, 0.f);
                #pragma unroll
                for (int m = 0; m < 19; m++)
                    fma4(acc, WV[e * 480 + k * 19 + m], *(const float4*)&Q[e * 2432 + m * 128 + c0]);
                float al = ALs[e * 8 + (c0 >> 4)];
                int b = (ki * 128 + c0) * 4 + e;
                EO[b + 0]  = acc.x * al;
                EO[b + 4]  = acc.y * al;
                EO[b + 8]  = acc.z * al;
                EO[b + 12] = acc.w * al;
            }
            __syncthreads();
            if (t < nk * 16) {
                int ki = t >> 4, o0 = (t & 15) * 4;
                int k = kb + ki;
                int l = (k == 0) ? 0 : (k < 4) ? 1 : (k < 9) ? 2 : (k < 16) ? 3 : 4;
                float4 pa0 = make_float4(0,0,0,0), pa1 = pa0, pa2 = pa0, pa3 = pa0;
                const float* eob = &EO[ki * 512];
                size_t base = (size_t)l * 8192 + o0;
                for (int c = 0; c < 128; c += 4) {
                    float4 p0 = LD4<BF>(proj_w, base + (size_t)(c + 0) * 64);
                    float4 p1 = LD4<BF>(proj_w, base + (size_t)(c + 1) * 64);
                    float4 p2 = LD4<BF>(proj_w, base + (size_t)(c + 2) * 64);
                    float4 p3 = LD4<BF>(proj_w, base + (size_t)(c + 3) * 64);
                    float4 v0 = *(const float4*)&eob[(c + 0) * 4];
                    float4 v1 = *(const float4*)&eob[(c + 1) * 4];
                    float4 v2 = *(const float4*)&eob[(c + 2) * 4];
                    float4 v3 = *(const float4*)&eob[(c + 3) * 4];
                    fma4(pa0, v0.x, p0); fma4(pa1, v0.y, p0); fma4(pa2, v0.z, p0); fma4(pa3, v0.w, p0);
                    fma4(pa0, v1.x, p1); fma4(pa1, v1.y, p1); fma4(pa2, v1.z, p1); fma4(pa3, v1.w, p1);
                    fma4(pa0, v2.x, p2); fma4(pa1, v2.y, p2); fma4(pa2, v2.z, p2); fma4(pa3, v2.w, p2);
                    fma4(pa0, v3.x, p3); fma4(pa1, v3.y, p3); fma4(pa2, v3.z, p3); fma4(pa3, v3.w, p3);
                }
                float* d0 = &accb[(size_t)rcv[0] * 1600 + k * 64 + o0];
                atomicAdd(d0 + 0, pa0.x); atomicAdd(d0 + 1, pa0.y);
                atomicAdd(d0 + 2, pa0.z); atomicAdd(d0 + 3, pa0.w);
                float* d1 = &accb[(size_t)rcv[1] * 1600 + k * 64 + o0];
                atomicAdd(d1 + 0, pa1.x); atomicAdd(d1 + 1, pa1.y);
                atomicAdd(d1 + 2, pa1.z); atomicAdd(d1 + 3, pa1.w);
                float* d2 = &accb[(size_t)rcv[2] * 1600 + k * 64 + o0];
                atomicAdd(d2 + 0, pa2.x); atomicAdd(d2 + 1, pa2.y);
                atomicAdd(d2 + 2, pa2.z); atomicAdd(d2 + 3, pa2.w);
                float* d3 = &accb[(size_t)rcv[3] * 1600 + k * 64 + o0];
                atomicAdd(d3 + 0, pa3.x); atomicAdd(d3 + 1, pa3.y);
                atomicAdd(d3 + 2, pa3.z); atomicAdd(d3 + 3, pa3.w);
            }
            __syncthreads();
        }
    }
}

// ---------------- bias + convert ----------------
template<bool BF>
__global__ void k_out(const float* __restrict__ accb, const void* __restrict__ proj_b,
                      void* __restrict__ out, const int* __restrict__ dtf) {
    if ((*dtf != 0) != BF) return;
    int i = blockIdx.x * 256 + threadIdx.x;
    if (i >= NNODES * 1600) return;
    int r = i % 1600;
    int m = r >> 6, o = r & 63;
    float v = accb[i] + ((m == 0) ? LD1<BF>(proj_b, o) : 0.0f);
    if (BF) ((bf16*)out)[i] = __float2bfloat16(v);
    else    ((float*)out)[i] = v;
}

extern "C" void kernel_launch(void* const* d_in, const int* in_sizes, int n_in,
                              void* d_out, int out_size, void* d_ws, size_t ws_size,
                              hipStream_t stream) {
    const void* node_feats = d_in[0];
    const void* edge_dist  = d_in[1];
    const void* wigner     = d_in[2];
    const void* wigner_inv = d_in[3];
    const void* to_grid    = d_in[4];
    const void* from_grid  = d_in[5];
    const void* emb_s      = d_in[6];
    const void* emb_r      = d_in[7];
    const void* rw1  = d_in[8];
    const void* rb1  = d_in[9];
    const void* rl1s = d_in[10];
    const void* rl1b = d_in[11];
    const void* rw2  = d_in[12];
    const void* rb2  = d_in[13];
    const void* rl2s = d_in[14];
    const void* rl2b = d_in[15];
    const void* rw3  = d_in[16];
    const void* rb3  = d_in[17];
    const void* c1w0 = d_in[18];
    const void* c1b0 = d_in[19];
    const void* c1w1 = d_in[20];
    const void* c1w2 = d_in[21];
    const void* c2w0 = d_in[22];
    const void* c2b0 = d_in[23];
    const void* c2w1 = d_in[24];
    const void* c2w2 = d_in[25];
    const void* an_s = d_in[26];
    const void* an_b = d_in[27];
    const void* adot = d_in[28];
    const void* proj_w = d_in[29];
    const void* proj_b = d_in[30];
    const int* species   = (const int*)d_in[31];
    const int* senders   = (const int*)d_in[32];
    const int* receivers = (const int*)d_in[33];

    char* ws = (char*)d_ws;
    float*    accb  = (float*)ws;                   // 32,000,000 B
    float*    alpha = (float*)(ws + 32000000);      // 800,000 B
    unsigned* nmax  = (unsigned*)(ws + 32800000);   // 160,000 B
    float*    nden  = (float*)(ws + 32960000);      // 160,000 B
    int*      dtf   = (int*)(ws + 33120000);        // 4 B

    k_detect<<<1, 64, 0, stream>>>(edge_dist, dtf);
    k_fill<<<(NNODES * 1600 + 255) / 256, 256, 0, stream>>>(accb, nden, nmax);

    k_alpha<true><<<NBLK, 256, 0, stream>>>(
        node_feats, edge_dist, wigner, emb_s, emb_r,
        rw1, rb1, rl1s, rl1b, rw2, rb2, rl2s, rl2b, rw3, rb3,
        c1w0, c1b0, an_s, an_b, adot, species, senders, receivers, dtf,
        alpha, nmax);
    k_alpha<false><<<NBLK, 256, 0, stream>>>(
        node_feats, edge_dist, wigner, emb_s, emb_r,
        rw1, rb1, rl1s, rl1b, rw2, rb2, rl2s, rl2b, rw3, rb3,
        c1w0, c1b0, an_s, an_b, adot, species, senders, receivers, dtf,
        alpha, nmax);

    k_exp<<<(EDGES * 8 + 255) / 256, 256, 0, stream>>>(receivers, nmax, alpha, nden);

    k_mega2<true><<<NBLK, 256, 0, stream>>>(
        node_feats, edge_dist, wigner, wigner_inv, to_grid, from_grid, emb_s, emb_r,
        rw1, rb1, rl1s, rl1b, rw2, rb2, rl2s, rl2b, rw3, rb3,
        c1w0, c1b0, c1w1, c1w2, c2w0, c2b0, c2w1, c2w2, proj_w,
        species, senders, receivers, dtf, alpha, nden, accb);
    k_mega2<false><<<NBLK, 256, 0, stream>>>(
        node_feats, edge_dist, wigner, wigner_inv, to_grid, from_grid, emb_s, emb_r,
        rw1, rb1, rl1s, rl1b, rw2, rb2, rl2s, rl2b, rw3, rb3,
        c1w0, c1b0, c1w1, c1w2, c2w0, c2b0, c2w1, c2w2, proj_w,
        species, senders, receivers, dtf, alpha, nden, accb);

    k_out<true><<<(NNODES * 1600 + 255) / 256, 256, 0, stream>>>(accb, proj_b, d_out, dtf);
    k_out<false><<<(NNODES * 1600 + 255) / 256, 256, 0, stream>>>(accb, proj_b, d_out, dtf);
}

// Round 6
// 4283.416 us; speedup vs baseline: 1.2252x; 1.1085x over previous
//
#include <hip/hip_runtime.h>
#include <hip/hip_bf16.h>

using bf16 = __hip_bfloat16;

#define EDGES 25000
#define NNODES 5000
#define EPB 4
#define NBLK (EDGES / EPB)

__device__ __forceinline__ float sigmf(float x) { return 1.0f / (1.0f + expf(-x)); }

template<bool BF>
__device__ __forceinline__ float LD1(const void* p, size_t i) {
    if (BF) return __bfloat162float(((const bf16*)p)[i]);
    else    return ((const float*)p)[i];
}

template<bool BF>
__device__ __forceinline__ float4 LD4(const void* p, size_t i) {
    if (BF) {
        ushort4 u = *reinterpret_cast<const ushort4*>((const bf16*)p + i);
        float4 r;
        r.x = __uint_as_float((unsigned)u.x << 16);
        r.y = __uint_as_float((unsigned)u.y << 16);
        r.z = __uint_as_float((unsigned)u.z << 16);
        r.w = __uint_as_float((unsigned)u.w << 16);
        return r;
    } else {
        return *reinterpret_cast<const float4*>((const float*)p + i);
    }
}

__device__ __forceinline__ void fma4(float4& a, float s, const float4& w) {
    a.x += s * w.x; a.y += s * w.y; a.z += s * w.z; a.w += s * w.w;
}

__device__ __forceinline__ void silu4(float4& a) {
    a.x *= sigmf(a.x); a.y *= sigmf(a.y); a.z *= sigmf(a.z); a.w *= sigmf(a.w);
}

// monotone float<->uint encoding for atomicMax on floats
__device__ __forceinline__ unsigned encF(float f) {
    unsigned b = __float_as_uint(f);
    return (b & 0x80000000u) ? ~b : (b | 0x80000000u);
}
__device__ __forceinline__ float decF(unsigned e) {
    unsigned b = (e & 0x80000000u) ? (e ^ 0x80000000u) : ~e;
    return __uint_as_float(b);
}
#define ENC_NEGINF 0x007FFFFFu

// 4-deep pipelined single-row MAC: acc[e] += act[e][i..i+3] * W[i..i+3][j0..j0+3]
#define STREAM4_1(Wptr, LDW, j0, ACTEXPR, NACC) \
    { \
        float4 w0 = LD4<BF>(Wptr, (size_t)(i + 0) * (LDW) + (j0)); \
        float4 w1 = LD4<BF>(Wptr, (size_t)(i + 1) * (LDW) + (j0)); \
        float4 w2 = LD4<BF>(Wptr, (size_t)(i + 2) * (LDW) + (j0)); \
        float4 w3 = LD4<BF>(Wptr, (size_t)(i + 3) * (LDW) + (j0)); \
        _Pragma("unroll") \
        for (int e = 0; e < NACC; e++) { \
            const float* qa = ACTEXPR; \
            float4 a0 = *(const float4*)qa; \
            fma4(acc[e], a0.x, w0); fma4(acc[e], a0.y, w1); \
            fma4(acc[e], a0.z, w2); fma4(acc[e], a0.w, w3); \
        } \
    }

// 4-deep pipelined two-row MAC into ra[e], rb[e]
#define STREAM4_2(Wptr, LDW, j0, ACTA, ACTB) \
    { \
        float4 w0 = LD4<BF>(Wptr, (size_t)(i + 0) * (LDW) + (j0)); \
        float4 w1 = LD4<BF>(Wptr, (size_t)(i + 1) * (LDW) + (j0)); \
        float4 w2 = LD4<BF>(Wptr, (size_t)(i + 2) * (LDW) + (j0)); \
        float4 w3 = LD4<BF>(Wptr, (size_t)(i + 3) * (LDW) + (j0)); \
        _Pragma("unroll") \
        for (int e = 0; e < EPB; e++) { \
            const float* pa = ACTA; \
            const float* pb = ACTB; \
            float4 a0 = *(const float4*)pa; \
            float4 b0 = *(const float4*)pb; \
            fma4(ra[e], a0.x, w0); fma4(ra[e], a0.y, w1); \
            fma4(ra[e], a0.z, w2); fma4(ra[e], a0.w, w3); \
            fma4(rb[e], b0.x, w0); fma4(rb[e], b0.y, w1); \
            fma4(rb[e], b0.z, w2); fma4(rb[e], b0.w, w3); \
        } \
    }

// ---------------- dtype detector ----------------
__global__ void k_detect(const void* edge_dist, int* flag) {
    if (threadIdx.x == 0 && blockIdx.x == 0) {
        const bf16* p = (const bf16*)edge_dist;
        int ok = 1;
        for (int i = 0; i < 256; i++) {
            float v = __bfloat162float(p[i]);
            if (!(v >= 0.0f && v <= 1.0f)) { ok = 0; break; }
        }
        *flag = ok;
    }
}

// ---------------- fill ----------------
__global__ void k_fill(float* accb, float* nden, unsigned* nmax) {
    int tid = blockIdx.x * 256 + threadIdx.x;
    if (tid < NNODES * 1600) accb[tid] = 0.0f;
    if (tid < NNODES * 8) { nden[tid] = 0.0f; nmax[tid] = ENC_NEGINF; }
}

// ---------------- alpha prepass: EPB=4, shared weights (unchanged, passing) -
template<bool BF>
__global__ __launch_bounds__(256, 3) void k_alpha(
    const void* __restrict__ node_feats, const void* __restrict__ edge_dist,
    const void* __restrict__ wigner, const void* __restrict__ emb_s,
    const void* __restrict__ emb_r,
    const void* __restrict__ rw1, const void* __restrict__ rb1,
    const void* __restrict__ rl1s, const void* __restrict__ rl1b,
    const void* __restrict__ rw2, const void* __restrict__ rb2,
    const void* __restrict__ rl2s, const void* __restrict__ rl2b,
    const void* __restrict__ rw3, const void* __restrict__ rb3,
    const void* __restrict__ c1w0, const void* __restrict__ c1b0,
    const void* __restrict__ an_s, const void* __restrict__ an_b,
    const void* __restrict__ adot,
    const int* __restrict__ species, const int* __restrict__ senders,
    const int* __restrict__ receivers, const int* __restrict__ dtf,
    float* __restrict__ alpha_out, unsigned* __restrict__ nmax)
{
    if ((*dtf != 0) != BF) return;
    __shared__ __align__(16) float sm[12160];
    float* XE   = sm;
    float* T1   = sm + 768;
    float* H1   = sm + 1024;
    float* T2   = sm + 1280;
    float* H2   = sm + 1536;
    float* rad0 = sm + 1792;
    float* x0   = sm + 4352;
    float* R    = sm + 6912;
    float* extraA = sm + 11136;

    const int t = threadIdx.x;
    const int e0 = blockIdx.x * EPB;
    const int eg = t >> 6, tt = t & 63;

    {
        int ee = e0 + eg;
        XE[eg * 192 + tt]       = LD1<BF>(edge_dist, (size_t)ee * 64 + tt);
        XE[eg * 192 + 64 + tt]  = LD1<BF>(emb_s, (size_t)species[senders[ee]] * 64 + tt);
        XE[eg * 192 + 128 + tt] = LD1<BF>(emb_r, (size_t)species[receivers[ee]] * 64 + tt);
    }
    __syncthreads();
    {
        float a = LD1<BF>(rb1, tt);
        #pragma unroll 4
        for (int k = 0; k < 192; k++) a += XE[eg * 192 + k] * LD1<BF>(rw1, k * 64 + tt);
        T1[eg * 64 + tt] = a;
    }
    __syncthreads();
    {
        float mu = 0.f;
        for (int k = 0; k < 64; k++) mu += T1[eg * 64 + k];
        mu *= (1.f / 64.f);
        float var = 0.f;
        for (int k = 0; k < 64; k++) { float d = T1[eg * 64 + k] - mu; var += d * d; }
        float xn = (T1[eg * 64 + tt] - mu) * rsqrtf(var * (1.f / 64.f) + 1e-6f) * LD1<BF>(rl1s, tt) + LD1<BF>(rl1b, tt);
        H1[eg * 64 + tt] = xn * sigmf(xn);
    }
    __syncthreads();
    {
        float a = LD1<BF>(rb2, tt);
        #pragma unroll 4
        for (int k = 0; k < 64; k++) a += H1[eg * 64 + k] * LD1<BF>(rw2, k * 64 + tt);
        T2[eg * 64 + tt] = a;
    }
    __syncthreads();
    {
        float mu = 0.f;
        for (int k = 0; k < 64; k++) mu += T2[eg * 64 + k];
        mu *= (1.f / 64.f);
        float var = 0.f;
        for (int k = 0; k < 64; k++) { float d = T2[eg * 64 + k] - mu; var += d * d; }
        float xn = (T2[eg * 64 + tt] - mu) * rsqrtf(var * (1.f / 64.f) + 1e-6f) * LD1<BF>(rl2s, tt) + LD1<BF>(rl2b, tt);
        H2[eg * 64 + tt] = xn * sigmf(xn);
    }
    __syncthreads();
    if (t < 160) {
        int j0 = t * 4;
        float4 acc[EPB];
        float4 bv = LD4<BF>(rb3, j0);
        #pragma unroll
        for (int e = 0; e < EPB; e++) acc[e] = bv;
        for (int i = 0; i < 64; i += 4)
            STREAM4_1(rw3, 1536, j0, &H2[e * 64 + i], EPB)
        #pragma unroll
        for (int e = 0; e < EPB; e++) *(float4*)&rad0[e * 640 + j0] = acc[e];
    }
    __syncthreads();
    {
        float* X  = R;
        float* WG = R + 3200;
        for (int e = 0; e < EPB; e++) {
            int s_ = senders[e0 + e], r_ = receivers[e0 + e];
            for (int q = t; q < 800; q += 256) {
                int k = q >> 5, c0 = (q & 31) * 4;
                float4 v = (c0 < 64) ? LD4<BF>(node_feats, (size_t)s_ * 1600 + k * 64 + c0)
                                     : LD4<BF>(node_feats, (size_t)r_ * 1600 + k * 64 + (c0 - 64));
                *(float4*)&X[q * 4] = v;
            }
            for (int i = t; i < 125; i += 256) WG[i] = LD1<BF>(wigner, (size_t)(e0 + e) * 475 + i);
            __syncthreads();
            if (t < 160) {
                int m = t >> 5, c0 = (t & 31) * 4;
                float4 acc = make_float4(0.f, 0.f, 0.f, 0.f);
                #pragma unroll
                for (int k = 0; k < 25; k++) fma4(acc, WG[m * 25 + k], *(const float4*)&X[k * 128 + c0]);
                float4 rv = *(const float4*)&rad0[e * 640 + t * 4];
                acc.x *= rv.x; acc.y *= rv.y; acc.z *= rv.z; acc.w *= rv.w;
                *(float4*)&x0[e * 640 + t * 4] = acc;
            }
            __syncthreads();
        }
    }
    {
        float* Y = R;
        int col = t & 63, kq = t >> 6;
        int j0 = 320 + col * 4;
        int ibase = kq * 160;
        float4 acc[EPB];
        #pragma unroll
        for (int e = 0; e < EPB; e++) acc[e] = make_float4(0.f, 0.f, 0.f, 0.f);
        for (int i = ibase; i < ibase + 160; i += 4)
            STREAM4_1(c1w0, 640, j0, &x0[e * 640 + i], EPB)
        __syncthreads();
        #pragma unroll
        for (int e = 0; e < EPB; e++) *(float4*)&Y[(e * 256 + kq * 64 + col) * 4] = acc[e];
        __syncthreads();
        {
            int e = t >> 6, c = t & 63;
            float4 s = LD4<BF>(c1b0, 320 + c * 4);
            #pragma unroll
            for (int q = 0; q < 4; q++) {
                float4 v = *(const float4*)&Y[(e * 256 + q * 64 + c) * 4];
                s.x += v.x; s.y += v.y; s.z += v.z; s.w += v.w;
            }
            *(float4*)&extraA[e * 256 + c * 4] = s;
        }
    }
    __syncthreads();
    if (t < 32) {
        int e = t >> 3, h = t & 7;
        float mu = 0.0f;
        for (int k = 0; k < 32; k++) mu += extraA[e * 256 + h * 32 + k];
        mu *= (1.0f / 32.0f);
        float var = 0.0f;
        for (int k = 0; k < 32; k++) { float d = extraA[e * 256 + h * 32 + k] - mu; var += d * d; }
        float rs = rsqrtf(var * (1.0f / 32.0f) + 1e-6f);
        float logit = 0.0f;
        for (int k = 0; k < 32; k++) {
            float xn = (extraA[e * 256 + h * 32 + k] - mu) * rs * LD1<BF>(an_s, k) + LD1<BF>(an_b, k);
            float slr = 0.6f * xn + 0.4f * xn * (2.0f * sigmf(xn) - 1.0f);
            logit += slr * LD1<BF>(adot, h * 32 + k);
        }
        int r = receivers[e0 + e];
        alpha_out[(size_t)(e0 + e) * 8 + h] = logit;
        atomicMax(&nmax[r * 8 + h], encF(logit));
    }
}

// ---------------- exp + denom ----------------
__global__ void k_exp(const int* __restrict__ receivers, const unsigned* __restrict__ nmax,
                      float* __restrict__ alpha, float* __restrict__ nden) {
    int tid = blockIdx.x * 256 + threadIdx.x;
    if (tid >= EDGES * 8) return;
    int e = tid >> 3, h = tid & 7;
    int r = receivers[e];
    float m = decF(nmax[r * 8 + h]);
    float ex = expf(alpha[tid] - m);
    alpha[tid] = ex;
    atomicAdd(&nden[r * 8 + h], ex);
}

// ---------------- mega2: 4 edges per block, 512 threads ----------------
// LDS map (floats, total 19744 = 78976 B -> 2 blocks/CU = 16 waves/CU):
//   Q   [0,9728)      : EF1[e][2432] (P2-P3) | G(6400)+S2(2432) (P4) | EF3[e][2432] (P5-P7)
//   C   [9728,14592)  : P1 scratch | P2 X+wg | EF2[e][1216] (P3-P4) | P5 staging | P7 WV+EO
//   RAD [13408,19552) : radial out [e][1536] (live P1-P2 only)
//   YF  [14592,19456) : P3 staging | FEATS[e][1216] (P4-P5)
//   GAT [19456,19712) : gating [e][64] (P3-P4)
//   ALs [19712,19744) : alpha scale [e][8] (P7)
template<bool BF>
__global__ __launch_bounds__(512, 4) void k_mega2(
    const void* __restrict__ node_feats, const void* __restrict__ edge_dist,
    const void* __restrict__ wigner, const void* __restrict__ wigner_inv,
    const void* __restrict__ to_grid, const void* __restrict__ from_grid,
    const void* __restrict__ emb_s, const void* __restrict__ emb_r,
    const void* __restrict__ rw1, const void* __restrict__ rb1,
    const void* __restrict__ rl1s, const void* __restrict__ rl1b,
    const void* __restrict__ rw2, const void* __restrict__ rb2,
    const void* __restrict__ rl2s, const void* __restrict__ rl2b,
    const void* __restrict__ rw3, const void* __restrict__ rb3,
    const void* __restrict__ c1w0, const void* __restrict__ c1b0,
    const void* __restrict__ c1w1, const void* __restrict__ c1w2,
    const void* __restrict__ c2w0, const void* __restrict__ c2b0,
    const void* __restrict__ c2w1, const void* __restrict__ c2w2,
    const void* __restrict__ proj_w,
    const int* __restrict__ species, const int* __restrict__ senders,
    const int* __restrict__ receivers, const int* __restrict__ dtf,
    const float* __restrict__ alpha, const float* __restrict__ nden,
    float* __restrict__ accb)
{
    if ((*dtf != 0) != BF) return;
    __shared__ __align__(16) float sm[19744];
    float* Q   = sm;
    float* C   = sm + 9728;
    float* RAD = sm + 13408;
    float* YF  = sm + 14592;
    float* GAT = sm + 19456;
    float* ALs = sm + 19712;

    const int t = threadIdx.x;
    const int e0 = blockIdx.x * EPB;
    int rcv[EPB];
    #pragma unroll
    for (int e = 0; e < EPB; e++) rcv[e] = receivers[e0 + e];

    // ---- P1: radial MLP ----
    {
        float* XE = C;
        float* T1 = C + 768;
        float* H1 = C + 1024;
        float* T2 = C + 1280;
        float* H2 = C + 1536;
        for (int i = t; i < 768; i += 512) {
            int e = i / 192, j = i - e * 192;
            int ee = e0 + e;
            float v;
            if (j < 64)       v = LD1<BF>(edge_dist, (size_t)ee * 64 + j);
            else if (j < 128) v = LD1<BF>(emb_s, (size_t)species[senders[ee]] * 64 + (j - 64));
            else              v = LD1<BF>(emb_r, (size_t)species[receivers[ee]] * 64 + (j - 128));
            XE[e * 192 + j] = v;
        }
        __syncthreads();
        const int eg = t >> 6, tt = t & 63;
        if (t < 256) {
            float a = LD1<BF>(rb1, tt);
            #pragma unroll 4
            for (int k = 0; k < 192; k++) a += XE[eg * 192 + k] * LD1<BF>(rw1, k * 64 + tt);
            T1[eg * 64 + tt] = a;
        }
        __syncthreads();
        if (t < 256) {
            float mu = 0.f;
            for (int k = 0; k < 64; k++) mu += T1[eg * 64 + k];
            mu *= (1.f / 64.f);
            float var = 0.f;
            for (int k = 0; k < 64; k++) { float d = T1[eg * 64 + k] - mu; var += d * d; }
            float xn = (T1[eg * 64 + tt] - mu) * rsqrtf(var * (1.f / 64.f) + 1e-6f) * LD1<BF>(rl1s, tt) + LD1<BF>(rl1b, tt);
            H1[eg * 64 + tt] = xn * sigmf(xn);
        }
        __syncthreads();
        if (t < 256) {
            float a = LD1<BF>(rb2, tt);
            #pragma unroll 4
            for (int k = 0; k < 64; k++) a += H1[eg * 64 + k] * LD1<BF>(rw2, k * 64 + tt);
            T2[eg * 64 + tt] = a;
        }
        __syncthreads();
        if (t < 256) {
            float mu = 0.f;
            for (int k = 0; k < 64; k++) mu += T2[eg * 64 + k];
            mu *= (1.f / 64.f);
            float var = 0.f;
            for (int k = 0; k < 64; k++) { float d = T2[eg * 64 + k] - mu; var += d * d; }
            float xn = (T2[eg * 64 + tt] - mu) * rsqrtf(var * (1.f / 64.f) + 1e-6f) * LD1<BF>(rl2s, tt) + LD1<BF>(rl2b, tt);
            H2[eg * 64 + tt] = xn * sigmf(xn);
        }
        __syncthreads();
        if (t < 384) {
            int j0 = t * 4;
            float4 acc[EPB];
            float4 bv = LD4<BF>(rb3, j0);
            #pragma unroll
            for (int e = 0; e < EPB; e++) acc[e] = bv;
            for (int i = 0; i < 64; i += 4)
                STREAM4_1(rw3, 1536, j0, &H2[e * 64 + i], EPB)
            #pragma unroll
            for (int e = 0; e < EPB; e++) *(float4*)&RAD[e * 1536 + j0] = acc[e];
        }
        __syncthreads();
    }

    // ---- P2: gather + wigner rotate + rad scale (per edge sequential) ----
    {
        float* X  = C;          // 3200
        float* WG = C + 3200;   // 480
        for (int e = 0; e < EPB; e++) {
            int s_ = senders[e0 + e], r_ = receivers[e0 + e];
            for (int q = t; q < 800; q += 512) {
                int k = q >> 5, c0 = (q & 31) * 4;
                float4 v = (c0 < 64) ? LD4<BF>(node_feats, (size_t)s_ * 1600 + k * 64 + c0)
                                     : LD4<BF>(node_feats, (size_t)r_ * 1600 + k * 64 + (c0 - 64));
                *(float4*)&X[q * 4] = v;
            }
            if (t < 475) WG[t] = LD1<BF>(wigner, (size_t)(e0 + e) * 475 + t);
            __syncthreads();
            for (int q = t; q < 608; q += 512) {
                int m = q >> 5, c0 = (q & 31) * 4;
                float4 acc = make_float4(0.f, 0.f, 0.f, 0.f);
                #pragma unroll
                for (int k = 0; k < 25; k++) fma4(acc, WG[m * 25 + k], *(const float4*)&X[k * 128 + c0]);
                int ri0;
                if (m < 5)       ri0 = m * 128 + c0;
                else if (m < 13) ri0 = 640 + ((m - 5) & 3) * 128 + c0;
                else             ri0 = 1152 + ((m - 13) % 3) * 128 + c0;
                float4 rv = *(const float4*)&RAD[e * 1536 + ri0];
                acc.x *= rv.x; acc.y *= rv.y; acc.z *= rv.z; acc.w *= rv.w;
                *(float4*)&Q[e * 2432 + q * 4] = acc;
            }
            __syncthreads();
        }
    }

    float4 ra[EPB], rb[EPB];

    // ---- P3: conv1 (512-thread schedule) ----
    {
        float* EF2 = C;
        float* YM  = YF;  // m1 staging [e][r][512] = 4096 floats
        // stage A: m1 with (row, colgroup, k-half) = 2x128x2 = 512 threads
        {
            int cg = t & 127, r = (t >> 7) & 1, kh = t >> 8;
            int j0 = cg * 4;
            float4 acc[EPB];
            #pragma unroll
            for (int e = 0; e < EPB; e++) acc[e] = make_float4(0.f, 0.f, 0.f, 0.f);
            int kb0 = 256 * kh;
            for (int i = kb0; i < kb0 + 256; i += 4)
                STREAM4_1(c1w1, 512, j0, &Q[e * 2432 + 640 + 512 * r + i], EPB)
            if (kh == 1) {
                #pragma unroll
                for (int e = 0; e < EPB; e++) *(float4*)&YM[(e * 2 + r) * 512 + j0] = acc[e];
            }
            __syncthreads();
            if (kh == 0) {
                #pragma unroll
                for (int e = 0; e < EPB; e++) {
                    float4 p = *(const float4*)&YM[(e * 2 + r) * 512 + j0];
                    acc[e].x += p.x; acc[e].y += p.y; acc[e].z += p.z; acc[e].w += p.w;
                    *(float4*)&YM[(e * 2 + r) * 512 + j0] = acc[e];
                }
            }
            __syncthreads();
            for (int u = t; u < 1024; u += 512) {
                int e = u >> 8, j = u & 255;
                float y0l = YM[(e * 2 + 0) * 512 + j];
                float y0u = YM[(e * 2 + 0) * 512 + 256 + j];
                float y1l = YM[(e * 2 + 1) * 512 + j];
                float y1u = YM[(e * 2 + 1) * 512 + 256 + j];
                EF2[e * 1216 + 320 + j] = y0l - y1u;
                EF2[e * 1216 + 576 + j] = y1l + y0u;
            }
            __syncthreads();
        }
        // stage B: m0 k-split (2 kh x 96 jq = 192 thr) || m2 single-row (192 thr)
        // NOTE: m0 has exactly 96 output f4-groups: 80 -> EF2[0,320), 16 -> GAT
        {
            float* MS  = YF;          // m0 kh=1 partials [e][96] f4 = 1536
            float* M2S = YF + 1536;   // m2 upper stage [e][r][48] f4 = 1536
            float4 keep[EPB];
            #pragma unroll
            for (int e = 0; e < EPB; e++) keep[e] = make_float4(0.f, 0.f, 0.f, 0.f);
            if (t < 192) {
                int kh = (t >= 96) ? 1 : 0;
                int jq = t - 96 * kh;  // 0..95
                int cmj = (jq < 80) ? jq * 4 : 576 + (jq - 80) * 4;
                float4 acc[EPB];
                #pragma unroll
                for (int e = 0; e < EPB; e++) acc[e] = make_float4(0.f, 0.f, 0.f, 0.f);
                int kb0 = kh * 320;
                for (int i = kb0; i < kb0 + 320; i += 4)
                    STREAM4_1(c1w0, 640, cmj, &Q[e * 2432 + i], EPB)
                if (kh) {
                    #pragma unroll
                    for (int e = 0; e < EPB; e++) *(float4*)&MS[(e * 96 + jq) * 4] = acc[e];
                } else {
                    #pragma unroll
                    for (int e = 0; e < EPB; e++) keep[e] = acc[e];
                }
            } else if (t < 384) {
                int u = t - 192;
                int r = (u >= 96) ? 1 : 0, cg = u - 96 * r;  // 0..95
                int j0 = cg * 4;
                float4 acc[EPB];
                #pragma unroll
                for (int e = 0; e < EPB; e++) acc[e] = make_float4(0.f, 0.f, 0.f, 0.f);
                int abase = 1664 + 384 * r;
                for (int i = 0; i < 384; i += 4)
                    STREAM4_1(c1w2, 384, j0, &Q[e * 2432 + abase + i], EPB)
                if (cg >= 48) {
                    #pragma unroll
                    for (int e = 0; e < EPB; e++)
                        *(float4*)&M2S[((e * 2 + r) * 48 + (cg - 48)) * 4] = acc[e];
                } else {
                    #pragma unroll
                    for (int e = 0; e < EPB; e++) keep[e] = acc[e];
                }
            }
            __syncthreads();
            if (t < 96) {  // m0 combine (kh=0 threads)
                int jq = t;
                int cmj = (jq < 80) ? jq * 4 : 576 + (jq - 80) * 4;
                float4 bv = LD4<BF>(c1b0, cmj);
                #pragma unroll
                for (int e = 0; e < EPB; e++) {
                    float4 p = *(const float4*)&MS[(e * 96 + jq) * 4];
                    float4 v;
                    v.x = keep[e].x + p.x + bv.x; v.y = keep[e].y + p.y + bv.y;
                    v.z = keep[e].z + p.z + bv.z; v.w = keep[e].w + p.w + bv.w;
                    if (jq < 80) *(float4*)&EF2[e * 1216 + jq * 4] = v;
                    else         *(float4*)&GAT[e * 64 + (jq - 80) * 4] = v;
                }
            } else if (t >= 192 && t < 384) {  // m2 combine (cg < 48)
                int u = t - 192;
                int r = (u >= 96) ? 1 : 0, cg = u - 96 * r;
                if (cg < 48) {
                    int j0 = cg * 4;
                    #pragma unroll
                    for (int e = 0; e < EPB; e++) {
                        float4 o = *(const float4*)&M2S[((e * 2 + (1 - r)) * 48 + cg) * 4];
                        float4 v;
                        if (r == 0) {
                            v.x = keep[e].x - o.x; v.y = keep[e].y - o.y;
                            v.z = keep[e].z - o.z; v.w = keep[e].w - o.w;
                            *(float4*)&EF2[e * 1216 + 832 + j0] = v;
                        } else {
                            v.x = keep[e].x + o.x; v.y = keep[e].y + o.y;
                            v.z = keep[e].z + o.z; v.w = keep[e].w + o.w;
                            *(float4*)&EF2[e * 1216 + 1024 + j0] = v;
                        }
                    }
                }
            }
            __syncthreads();
        }
    }

    // ---- P4: grid nonlinearity (per edge, 512-wide) ----
    {
        float* FE  = YF;        // FEATS [e][1216]
        float* G   = Q;         // 100 x 64 = 6400
        float* S2  = Q + 6400;  // 608 f4 = 2432
        float* EF2 = C;
        for (int e = 0; e < EPB; e++) {
            for (int idx = t; idx < 1600; idx += 512) {
                int gi = idx >> 4, c0 = (idx & 15) * 4;
                float4 acc = make_float4(0.f, 0.f, 0.f, 0.f);
                #pragma unroll
                for (int m = 0; m < 19; m++)
                    fma4(acc, LD1<BF>(to_grid, gi * 19 + m),
                         *(const float4*)&EF2[e * 1216 + m * 64 + c0]);
                silu4(acc);
                *(float4*)&G[gi * 64 + c0] = acc;
            }
            __syncthreads();
            for (int idx = t; idx < 608; idx += 512) {
                int m = idx >> 5, cq = (idx >> 1) & 15, h = idx & 1, c0 = cq * 4;
                int g0 = h * 50;
                float4 acc = make_float4(0.f, 0.f, 0.f, 0.f);
                #pragma unroll 5
                for (int gi = 0; gi < 50; gi++)
                    fma4(acc, LD1<BF>(from_grid, (g0 + gi) * 19 + m),
                         *(const float4*)&G[(g0 + gi) * 64 + c0]);
                *(float4*)&S2[idx * 4] = acc;
            }
            __syncthreads();
            if (t < 304) {
                int m = t >> 4, cq = t & 15;
                int pb = (m * 32 + cq * 2) * 4;
                float4 a = *(const float4*)&S2[pb];
                float4 b = *(const float4*)&S2[pb + 4];
                a.x += b.x; a.y += b.y; a.z += b.z; a.w += b.w;
                *(float4*)&FE[e * 1216 + m * 64 + cq * 4] = a;
            }
            __syncthreads();
        }
        if (t < 64) {
            #pragma unroll
            for (int e = 0; e < EPB; e++) { float x = GAT[e * 64 + t]; FE[e * 1216 + t] = x * sigmf(x); }
        }
        __syncthreads();
    }

    // ---- P5: conv2 -> EF3 in Q (512-thread schedule) ----
    {
        float* FE  = YF;
        float* M1S = C;   // m1 upper stage [e][r][128] f4 = 4096
        float4 keep[EPB];
        {
            int cg = t & 255, r = t >> 8;
            int j0 = cg * 4;
            float4 acc[EPB];
            #pragma unroll
            for (int e = 0; e < EPB; e++) acc[e] = make_float4(0.f, 0.f, 0.f, 0.f);
            int abase = 320 + 256 * r;
            for (int i = 0; i < 256; i += 4)
                STREAM4_1(c2w1, 1024, j0, &FE[e * 1216 + abase + i], EPB)
            if (cg >= 128) {
                #pragma unroll
                for (int e = 0; e < EPB; e++)
                    *(float4*)&M1S[((e * 2 + r) * 128 + (cg - 128)) * 4] = acc[e];
            } else {
                #pragma unroll
                for (int e = 0; e < EPB; e++) keep[e] = acc[e];
            }
            __syncthreads();
            if (cg < 128) {
                #pragma unroll
                for (int e = 0; e < EPB; e++) {
                    float4 o = *(const float4*)&M1S[((e * 2 + (1 - r)) * 128 + cg) * 4];
                    float4 v;
                    if (r == 0) {
                        v.x = keep[e].x - o.x; v.y = keep[e].y - o.y;
                        v.z = keep[e].z - o.z; v.w = keep[e].w - o.w;
                        *(float4*)&Q[e * 2432 + 640 + j0] = v;
                    } else {
                        v.x = keep[e].x + o.x; v.y = keep[e].y + o.y;
                        v.z = keep[e].z + o.z; v.w = keep[e].w + o.w;
                        *(float4*)&Q[e * 2432 + 1152 + j0] = v;
                    }
                }
            }
            __syncthreads();
        }
        // stage B: m0 (t<160 full-k) || m2 both-rows (160<=t<352)
        {
            float* M2S = C;  // m2 upper stage [e][r][96] f4 = 3072
            if (t < 160) {
                int j0 = t * 4;
                float4 acc[EPB];
                float4 bv = LD4<BF>(c2b0, j0);
                #pragma unroll
                for (int e = 0; e < EPB; e++) acc[e] = bv;
                for (int i = 0; i < 320; i += 4)
                    STREAM4_1(c2w0, 640, j0, &FE[e * 1216 + i], EPB)
                #pragma unroll
                for (int e = 0; e < EPB; e++) *(float4*)&Q[e * 2432 + j0] = acc[e];
            } else if (t < 352) {
                int cg = t - 160;  // 0..191
                int j0 = cg * 4;
                #pragma unroll
                for (int e = 0; e < EPB; e++) { ra[e] = make_float4(0,0,0,0); rb[e] = make_float4(0,0,0,0); }
                for (int i = 0; i < 192; i += 4)
                    STREAM4_2(c2w2, 768, j0, &FE[e * 1216 + 832 + i], &FE[e * 1216 + 1024 + i])
                if (cg >= 96) {
                    #pragma unroll
                    for (int e = 0; e < EPB; e++) {
                        *(float4*)&M2S[((e * 2 + 0) * 96 + (cg - 96)) * 4] = ra[e];
                        *(float4*)&M2S[((e * 2 + 1) * 96 + (cg - 96)) * 4] = rb[e];
                    }
                }
            }
            __syncthreads();
            if (t >= 160 && t < 256) {
                int cg = t - 160;  // 0..95
                int j0 = cg * 4;
                #pragma unroll
                for (int e = 0; e < EPB; e++) {
                    float4 y1u = *(const float4*)&M2S[((e * 2 + 1) * 96 + cg) * 4];
                    float4 y0u = *(const float4*)&M2S[((e * 2 + 0) * 96 + cg) * 4];
                    float4 r, im;
                    r.x = ra[e].x - y1u.x; r.y = ra[e].y - y1u.y;
                    r.z = ra[e].z - y1u.z; r.w = ra[e].w - y1u.w;
                    im.x = rb[e].x + y0u.x; im.y = rb[e].y + y0u.y;
                    im.z = rb[e].z + y0u.z; im.w = rb[e].w + y0u.w;
                    *(float4*)&Q[e * 2432 + 1664 + j0] = r;
                    *(float4*)&Q[e * 2432 + 2048 + j0] = im;
                }
            }
            __syncthreads();
        }
    }

    // ---- P7: wigner_inv rotate + alpha + fused proj (edge-split proj) ----
    {
        float* WV = C;           // [e][480]
        float* EO = C + 1920;    // up to 13*512 = 6656 floats
        if (t < 32) {
            int h = t & 7;
            int ee = e0 + (t >> 3);
            ALs[t] = alpha[(size_t)ee * 8 + h] / (nden[(size_t)receivers[ee] * 8 + h] + 1e-16f);
        }
        for (int i = t; i < 1900; i += 512) {
            int e = i / 475, j = i - e * 475;
            WV[e * 480 + j] = LD1<BF>(wigner_inv, (size_t)(e0 + e) * 475 + j);
        }
        __syncthreads();
        for (int kb = 0; kb < 25; kb += 13) {
            const int nk = (kb == 0) ? 13 : 12;
            for (int u = t; u < nk * 128; u += 512) {
                int e = u & 3, idx = u >> 2;
                int ki = idx >> 5, c0 = (idx & 31) * 4;
                int k = kb + ki;
                float4 acc = make_float4(0.f, 0.f, 0.f, 0.f);
                #pragma unroll
                for (int m = 0; m < 19; m++)
                    fma4(acc, WV[e * 480 + k * 19 + m], *(const float4*)&Q[e * 2432 + m * 128 + c0]);
                float al = ALs[e * 8 + (c0 >> 4)];
                int b = (ki * 128 + c0) * 4 + e;
                EO[b + 0]  = acc.x * al;
                EO[b + 4]  = acc.y * al;
                EO[b + 8]  = acc.z * al;
                EO[b + 12] = acc.w * al;
            }
            __syncthreads();
            if (t < nk * 32) {
                int ki = t >> 5;
                int rem = t & 31;
                int o = rem >> 1, eh = rem & 1;
                int o0 = o * 4;
                int k = kb + ki;
                int l = (k == 0) ? 0 : (k < 4) ? 1 : (k < 9) ? 2 : (k < 16) ? 3 : 4;
                float4 pa0 = make_float4(0,0,0,0), pa1 = pa0;
                const float* eob = &EO[ki * 512 + eh * 2];
                size_t base = (size_t)l * 8192 + o0;
                for (int c = 0; c < 128; c += 4) {
                    float4 p0 = LD4<BF>(proj_w, base + (size_t)(c + 0) * 64);
                    float4 p1 = LD4<BF>(proj_w, base + (size_t)(c + 1) * 64);
                    float4 p2 = LD4<BF>(proj_w, base + (size_t)(c + 2) * 64);
                    float4 p3 = LD4<BF>(proj_w, base + (size_t)(c + 3) * 64);
                    fma4(pa0, eob[(c + 0) * 4], p0); fma4(pa1, eob[(c + 0) * 4 + 1], p0);
                    fma4(pa0, eob[(c + 1) * 4], p1); fma4(pa1, eob[(c + 1) * 4 + 1], p1);
                    fma4(pa0, eob[(c + 2) * 4], p2); fma4(pa1, eob[(c + 2) * 4 + 1], p2);
                    fma4(pa0, eob[(c + 3) * 4], p3); fma4(pa1, eob[(c + 3) * 4 + 1], p3);
                }
                int ep = eh * 2;
                float* d0 = &accb[(size_t)rcv[ep] * 1600 + k * 64 + o0];
                atomicAdd(d0 + 0, pa0.x); atomicAdd(d0 + 1, pa0.y);
                atomicAdd(d0 + 2, pa0.z); atomicAdd(d0 + 3, pa0.w);
                float* d1 = &accb[(size_t)rcv[ep + 1] * 1600 + k * 64 + o0];
                atomicAdd(d1 + 0, pa1.x); atomicAdd(d1 + 1, pa1.y);
                atomicAdd(d1 + 2, pa1.z); atomicAdd(d1 + 3, pa1.w);
            }
            __syncthreads();
        }
    }
}

// ---------------- bias + convert ----------------
template<bool BF>
__global__ void k_out(const float* __restrict__ accb, const void* __restrict__ proj_b,
                      void* __restrict__ out, const int* __restrict__ dtf) {
    if ((*dtf != 0) != BF) return;
    int i = blockIdx.x * 256 + threadIdx.x;
    if (i >= NNODES * 1600) return;
    int r = i % 1600;
    int m = r >> 6, o = r & 63;
    float v = accb[i] + ((m == 0) ? LD1<BF>(proj_b, o) : 0.0f);
    if (BF) ((bf16*)out)[i] = __float2bfloat16(v);
    else    ((float*)out)[i] = v;
}

extern "C" void kernel_launch(void* const* d_in, const int* in_sizes, int n_in,
                              void* d_out, int out_size, void* d_ws, size_t ws_size,
                              hipStream_t stream) {
    const void* node_feats = d_in[0];
    const void* edge_dist  = d_in[1];
    const void* wigner     = d_in[2];
    const void* wigner_inv = d_in[3];
    const void* to_grid    = d_in[4];
    const void* from_grid  = d_in[5];
    const void* emb_s      = d_in[6];
    const void* emb_r      = d_in[7];
    const void* rw1  = d_in[8];
    const void* rb1  = d_in[9];
    const void* rl1s = d_in[10];
    const void* rl1b = d_in[11];
    const void* rw2  = d_in[12];
    const void* rb2  = d_in[13];
    const void* rl2s = d_in[14];
    const void* rl2b = d_in[15];
    const void* rw3  = d_in[16];
    const void* rb3  = d_in[17];
    const void* c1w0 = d_in[18];
    const void* c1b0 = d_in[19];
    const void* c1w1 = d_in[20];
    const void* c1w2 = d_in[21];
    const void* c2w0 = d_in[22];
    const void* c2b0 = d_in[23];
    const void* c2w1 = d_in[24];
    const void* c2w2 = d_in[25];
    const void* an_s = d_in[26];
    const void* an_b = d_in[27];
    const void* adot = d_in[28];
    const void* proj_w = d_in[29];
    const void* proj_b = d_in[30];
    const int* species   = (const int*)d_in[31];
    const int* senders   = (const int*)d_in[32];
    const int* receivers = (const int*)d_in[33];

    char* ws = (char*)d_ws;
    float*    accb  = (float*)ws;                   // 32,000,000 B
    float*    alpha = (float*)(ws + 32000000);      // 800,000 B
    unsigned* nmax  = (unsigned*)(ws + 32800000);   // 160,000 B
    float*    nden  = (float*)(ws + 32960000);      // 160,000 B
    int*      dtf   = (int*)(ws + 33120000);        // 4 B

    k_detect<<<1, 64, 0, stream>>>(edge_dist, dtf);
    k_fill<<<(NNODES * 1600 + 255) / 256, 256, 0, stream>>>(accb, nden, nmax);

    k_alpha<true><<<NBLK, 256, 0, stream>>>(
        node_feats, edge_dist, wigner, emb_s, emb_r,
        rw1, rb1, rl1s, rl1b, rw2, rb2, rl2s, rl2b, rw3, rb3,
        c1w0, c1b0, an_s, an_b, adot, species, senders, receivers, dtf,
        alpha, nmax);
    k_alpha<false><<<NBLK, 256, 0, stream>>>(
        node_feats, edge_dist, wigner, emb_s, emb_r,
        rw1, rb1, rl1s, rl1b, rw2, rb2, rl2s, rl2b, rw3, rb3,
        c1w0, c1b0, an_s, an_b, adot, species, senders, receivers, dtf,
        alpha, nmax);

    k_exp<<<(EDGES * 8 + 255) / 256, 256, 0, stream>>>(receivers, nmax, alpha, nden);

    k_mega2<true><<<NBLK, 512, 0, stream>>>(
        node_feats, edge_dist, wigner, wigner_inv, to_grid, from_grid, emb_s, emb_r,
        rw1, rb1, rl1s, rl1b, rw2, rb2, rl2s, rl2b, rw3, rb3,
        c1w0, c1b0, c1w1, c1w2, c2w0, c2b0, c2w1, c2w2, proj_w,
        species, senders, receivers, dtf, alpha, nden, accb);
    k_mega2<false><<<NBLK, 512, 0, stream>>>(
        node_feats, edge_dist, wigner, wigner_inv, to_grid, from_grid, emb_s, emb_r,
        rw1, rb1, rl1s, rl1b, rw2, rb2, rl2s, rl2b, rw3, rb3,
        c1w0, c1b0, c1w1, c1w2, c2w0, c2b0, c2w1, c2w2, proj_w,
        species, senders, receivers, dtf, alpha, nden, accb);

    k_out<true><<<(NNODES * 1600 + 255) / 256, 256, 0, stream>>>(accb, proj_b, d_out, dtf);
    k_out<false><<<(NNODES * 1600 + 255) / 256, 256, 0, stream>>>(accb, proj_b, d_out, dtf);
}